// Round 2
// baseline (399.454 us; speedup 1.0000x reference)
//
#include <hip/hip_runtime.h>
#include <math.h>

#define L_SEQ 2048
#define E_DIM 2048
#define H_NUM 16
#define D_HEAD 128

typedef __attribute__((ext_vector_type(8))) _Float16 half8;
typedef __attribute__((ext_vector_type(4))) _Float16 half4;
typedef __attribute__((ext_vector_type(4))) float floatx4;

// async global->LDS, 16B per lane. LDS dest is wave-uniform base + lane*16.
static __device__ __forceinline__ void gload16(const void* g, void* lds) {
  __builtin_amdgcn_global_load_lds(
      (const __attribute__((address_space(1))) void*)g,
      (__attribute__((address_space(3))) void*)lds, 16, 0, 0);
}

// ---------------------------------------------------------------------------
// Fused fp32 -> fp16 conversion of x, in_proj_w, out_proj_w (one launch).
// ---------------------------------------------------------------------------
__global__ __launch_bounds__(256)
void cvt3_f32_f16(const float* __restrict__ a, _Float16* __restrict__ oa, int na,
                  const float* __restrict__ b, _Float16* __restrict__ ob, int nb,
                  const float* __restrict__ c, _Float16* __restrict__ oc, int nc) {
  int i = (blockIdx.x * 256 + threadIdx.x) * 8;
  const float* src;
  _Float16* dst;
  if (i < na) {
    src = a + i; dst = oa + i;
  } else if (i < na + nb) {
    src = b + (i - na); dst = ob + (i - na);
  } else if (i < na + nb + nc) {
    src = c + (i - na - nb); dst = oc + (i - na - nb);
  } else {
    return;
  }
  float4 p = *(const float4*)src;
  float4 q = *(const float4*)(src + 4);
  half8 h = {(_Float16)p.x, (_Float16)p.y, (_Float16)p.z, (_Float16)p.w,
             (_Float16)q.x, (_Float16)q.y, (_Float16)q.z, (_Float16)q.w};
  *(half8*)dst = h;
}

// ---------------------------------------------------------------------------
// MFMA GEMM (NT) v2 (R7-verified): unchanged this round.
// ---------------------------------------------------------------------------
template <int TM, int TN, int WR, int WC, int EPI>
__global__ __launch_bounds__(256)
void gemm_mfma(const _Float16* __restrict__ A, const _Float16* __restrict__ B,
               const float* __restrict__ bias, float* __restrict__ C,
               _Float16* __restrict__ qk, _Float16* __restrict__ vt,
               int M, int N, int K) {
  constexpr int RT = TM / (16 * WR);
  constexpr int CT = TN / (16 * WC);
  constexpr int ACH = TM / 8;
  constexpr int NCH = (TM + TN) / 32;

  __shared__ _Float16 As[2][TM * 64];
  __shared__ _Float16 Bs[2][TN * 64];

  const int tid = threadIdx.x;
  const int wave = tid >> 6, lane = tid & 63;
  const int l15 = lane & 15, quad = lane >> 4;
  const int wr = wave / WC, wc = wave % WC;
  const int row0 = blockIdx.y * TM, col0 = blockIdx.x * TN;

  const int srow = lane >> 3;
  const int gc = (lane & 7) ^ srow;

  auto stage = [&](int buf, int k0) {
#pragma unroll
    for (int c = 0; c < NCH; ++c) {
      int chunk = wave * NCH + c;
      if (chunk < ACH) {
        int row = chunk * 8 + srow;
        gload16((const char*)(A + (size_t)(row0 + row) * K + k0) + gc * 16,
                (char*)&As[buf][0] + chunk * 1024);
      } else {
        int bch = chunk - ACH;
        int row = bch * 8 + srow;
        gload16((const char*)(B + (size_t)(col0 + row) * K + k0) + gc * 16,
                (char*)&Bs[buf][0] + bch * 1024);
      }
    }
  };

  floatx4 acc[RT][CT];
#pragma unroll
  for (int i = 0; i < RT; ++i)
#pragma unroll
    for (int j = 0; j < CT; ++j) acc[i][j] = (floatx4){0.f, 0.f, 0.f, 0.f};

  const int niter = K / 64;
  stage(0, 0);

  for (int it = 0; it < niter; ++it) {
    const int cur = it & 1;
    __syncthreads();
    if (it + 1 < niter) stage(cur ^ 1, (it + 1) * 64);

#pragma unroll
    for (int ks = 0; ks < 2; ++ks) {
      half8 af[RT], bf[CT];
#pragma unroll
      for (int t = 0; t < RT; ++t) {
        int r = wr * (16 * RT) + t * 16 + l15;
        af[t] = *(const half8*)&As[cur][r * 64 + (((ks * 4 + quad) ^ (r & 7)) * 8)];
      }
#pragma unroll
      for (int t = 0; t < CT; ++t) {
        int r = wc * (16 * CT) + t * 16 + l15;
        bf[t] = *(const half8*)&Bs[cur][r * 64 + (((ks * 4 + quad) ^ (r & 7)) * 8)];
      }
#pragma unroll
      for (int tr = 0; tr < RT; ++tr)
#pragma unroll
        for (int tc = 0; tc < CT; ++tc)
          acc[tr][tc] = __builtin_amdgcn_mfma_f32_16x16x32_f16(
              af[tr], bf[tc], acc[tr][tc], 0, 0, 0);
    }
  }

  const int crow = row0 + wr * (16 * RT);
  const int ccol = col0 + wc * (16 * CT);

  if (EPI == 0) {
#pragma unroll
    for (int tc = 0; tc < CT; ++tc) {
      int col = ccol + tc * 16 + l15;
      float bb = bias[col];
#pragma unroll
      for (int tr = 0; tr < RT; ++tr)
#pragma unroll
        for (int r = 0; r < 4; ++r)
          C[(size_t)(crow + tr * 16 + quad * 4 + r) * N + col] =
              acc[tr][tc][r] + bb;
    }
  } else if (col0 < 2 * E_DIM) {
#pragma unroll
    for (int tc = 0; tc < CT; ++tc) {
      int col = ccol + tc * 16 + l15;
      float bb = bias[col];
#pragma unroll
      for (int tr = 0; tr < RT; ++tr)
#pragma unroll
        for (int r = 0; r < 4; ++r)
          qk[(size_t)(crow + tr * 16 + quad * 4 + r) * (2 * E_DIM) + col] =
              (_Float16)(acc[tr][tc][r] + bb);
    }
  } else {
#pragma unroll
    for (int tc = 0; tc < CT; ++tc) {
      int col = ccol + tc * 16 + l15;
      float bb = bias[col];
      int vrow = col - 2 * E_DIM;
#pragma unroll
      for (int tr = 0; tr < RT; ++tr) {
        int rbase = crow + tr * 16 + quad * 4;
        half4 h = {(_Float16)(acc[tr][tc][0] + bb), (_Float16)(acc[tr][tc][1] + bb),
                   (_Float16)(acc[tr][tc][2] + bb), (_Float16)(acc[tr][tc][3] + bb)};
        *(half4*)&vt[(size_t)vrow * L_SEQ + rbase] = h;
      }
    }
  }
}

// ---------------------------------------------------------------------------
// MFMA flash attention v7 — occupancy-fixed.
// Grid (H, L/128) = 256 blocks, 1024 thr = 16 waves -> 4 waves/SIMD
// (v6 was latency-bound at 2 waves/SIMD; all pipes <30% busy).
// Wave (g = wave>>2, pp = wave&3): 32 q-rows (two 16-row MFMA sub-tiles),
// key-tiles of parity pp (KVBLK=32; 16 of 64 tiles). Partials merged at the
// end (no-max softmax => merge is a plain sum).
//  - K/V 8-slot LDS (2 staging generations x 4 parities), 8KB/slot = 128KB,
//    staged via global_load_lds with XOR-pre-swizzled global source (linear
//    LDS dest), read with the same XOR swizzle.
//  - PV uses mfma_f32_16x16x16f16: S^T fragment layout IS the x16 A-fragment
//    layout, so P never touches LDS.
//  - bias loaded at point of use (keeps peak VGPR <= 128 for 4 waves/SIMD).
// ---------------------------------------------------------------------------
__global__ __launch_bounds__(1024, 4)
void attn_mfma(const _Float16* __restrict__ qk, const _Float16* __restrict__ vt,
               const float* __restrict__ bias, _Float16* __restrict__ ctx) {
  const int h = blockIdx.x;
  const int q0 = blockIdx.y * 128;
  const int tid = threadIdx.x;
  const int wave = tid >> 6;
  const int lane = tid & 63;
  const int l15 = lane & 15;
  const int quad = lane >> 4;
  const int g = wave >> 2;   // row-group: rows q0 + g*32 .. +31
  const int pp = wave & 3;   // key-tile parity (mod 4)

  // ksmem: 8 slots x [32 key][128 d] halfs (8KB each), chunk swizzle c^(row&7)
  // vsmem: 8 slots x [128 d][32 key] halfs (8KB each), chunk swizzle c^(row&3)
  __shared__ __align__(16) char smem[131072];
  char* const ksmem = smem;
  char* const vsmem = smem + 65536;

  const int qrow = q0 + g * 32;

  // Q fragments (B-operand of S^T = K*Q^T): qa[u][ks]
  half8 qa[2][4];
#pragma unroll
  for (int u = 0; u < 2; ++u) {
    const _Float16* qp =
        qk + (size_t)(qrow + u * 16 + l15) * (2 * E_DIM) + h * D_HEAD + quad * 8;
#pragma unroll
    for (int ks = 0; ks < 4; ++ks) qa[u][ks] = *(const half8*)(qp + ks * 32);
  }

  float l_acc[2] = {0.f, 0.f};
  floatx4 o[2][8];
#pragma unroll
  for (int u = 0; u < 2; ++u)
#pragma unroll
    for (int t = 0; t < 8; ++t) o[u][t] = (floatx4){0.f, 0.f, 0.f, 0.f};

  const float scale = 0.088388347648318447f;  // 1/sqrt(128)

  // stage one 128-key generation (4 tiles of 32) into slots sb..sb+3.
  // 4096 16B-chunks (4x K-tile 512 + 4x V-tile 512) over 1024 threads.
  auto stage_quad = [&](int kt2, int sb) {
#pragma unroll
    for (int c = 0; c < 4; ++c) {
      int mb = c * 1024 + (tid & ~63);  // wave-uniform chunk base
      int m = mb + (tid & 63);
      if (mb < 2048) {  // K region
        int sub = mb >> 9;
        int idx = m & 511, idx0 = mb & 511;
        int row = idx >> 4, cc = idx & 15;
        gload16(qk + (size_t)(kt2 + sub * 32 + row) * (2 * E_DIM) + E_DIM +
                    h * D_HEAD + ((cc ^ (row & 7)) * 8),
                ksmem + (sb + sub) * 8192 + idx0 * 16);
      } else {  // V region
        int mb2 = mb - 2048;
        int sub = mb2 >> 9;
        int idx = (m - 2048) & 511, idx0 = mb2 & 511;
        int row = idx >> 2, cc = idx & 3;
        gload16(vt + (size_t)(h * D_HEAD + row) * L_SEQ + kt2 + sub * 32 +
                    ((cc ^ (row & 3)) * 8),
                vsmem + (sb + sub) * 8192 + idx0 * 16);
      }
    }
  };

  stage_quad(0, 0);

#pragma unroll 2
  for (int s = 0; s < 16; ++s) {
    const int kt = s * 128 + pp * 32;        // this wave's key-tile base
    const int slot = (s & 1) * 4 + pp;
    __syncthreads();  // gen-s staging drained; gen-(s+1) slots' readers done

    if (s < 15) stage_quad((s + 1) * 128, ((s + 1) & 1) * 4);

    // ---- S^T = K*Q^T : col=l15=q, row=quad*4+r=key (within 16-block t4) ----
    const char* ksb = ksmem + slot * 8192;
    floatx4 st[2][2];
#pragma unroll
    for (int u = 0; u < 2; ++u)
#pragma unroll
      for (int t4 = 0; t4 < 2; ++t4) st[u][t4] = (floatx4){0.f, 0.f, 0.f, 0.f};
#pragma unroll
    for (int ks = 0; ks < 4; ++ks)
#pragma unroll
      for (int t4 = 0; t4 < 2; ++t4) {
        int row = t4 * 16 + l15;
        half8 kf = *(const half8*)(ksb + row * 256 +
                                   (((4 * ks + quad) ^ (row & 7)) * 16));
        st[0][t4] = __builtin_amdgcn_mfma_f32_16x16x32_f16(kf, qa[0][ks],
                                                           st[0][t4], 0, 0, 0);
        st[1][t4] = __builtin_amdgcn_mfma_f32_16x16x32_f16(kf, qa[1][ks],
                                                           st[1][t4], 0, 0, 0);
      }

    // ---- softmax (no max subtraction); hp = x16 A-fragment directly ----
    half4 hp[2][2];
#pragma unroll
    for (int u = 0; u < 2; ++u) {
      float ls = 0.f;
#pragma unroll
      for (int t4 = 0; t4 < 2; ++t4) {
        floatx4 bq = *(const floatx4*)&bias[(size_t)(qrow + u * 16 + l15) * L_SEQ +
                                            kt + t4 * 16 + quad * 4];
        float p0 = __expf(fmaf(st[u][t4][0], scale, bq[0]));
        float p1 = __expf(fmaf(st[u][t4][1], scale, bq[1]));
        float p2 = __expf(fmaf(st[u][t4][2], scale, bq[2]));
        float p3 = __expf(fmaf(st[u][t4][3], scale, bq[3]));
        ls += (p0 + p1) + (p2 + p3);
        hp[u][t4] = (half4){(_Float16)p0, (_Float16)p1, (_Float16)p2, (_Float16)p3};
      }
      ls += __shfl_xor(ls, 16);
      ls += __shfl_xor(ls, 32);
      l_acc[u] += ls;
    }

    // ---- O += P V via x16 MFMA (P stays in registers) ----
    const char* vsb = vsmem + slot * 8192;
#pragma unroll
    for (int tk = 0; tk < 2; ++tk)
#pragma unroll
      for (int td = 0; td < 8; ++td) {
        int row = td * 16 + l15;
        half4 vf = *(const half4*)(vsb + row * 64 +
                                   (((2 * tk + (quad >> 1)) ^ (row & 3)) * 16) +
                                   (quad & 1) * 8);
        o[0][td] = __builtin_amdgcn_mfma_f32_16x16x16f16(hp[0][tk], vf,
                                                         o[0][td], 0, 0, 0);
        o[1][td] = __builtin_amdgcn_mfma_f32_16x16x16f16(hp[1][tk], vf,
                                                         o[1][td], 0, 0, 0);
      }
  }

  // ---- 4-parity merge (plain sums; no-max softmax) + epilogue ----
  // obuf: [g][j<2][128 col][20 pad] floats = 80KB; lbuf after it (2KB).
  float* obuf = (float*)smem;
  float* lbuf = (float*)(smem + 81920);
  __syncthreads();  // all K/V slot readers done before LDS reuse
  if (quad == 0) {
    lbuf[((g * 4 + pp) * 2 + 0) * 16 + l15] = l_acc[0];
    lbuf[((g * 4 + pp) * 2 + 1) * 16 + l15] = l_acc[1];
  }

#pragma unroll
  for (int u = 0; u < 2; ++u) {
    __syncthreads();
    if (pp >= 2) {
#pragma unroll
      for (int t = 0; t < 8; ++t)
        *(floatx4*)&obuf[(size_t)((g * 2 + (pp - 2)) * 128 + t * 16 + l15) * 20 +
                         quad * 4] = o[u][t];
    }
    __syncthreads();
    if (pp < 2) {
#pragma unroll
      for (int t = 0; t < 8; ++t) {
        floatx4 part = *(const floatx4*)&obuf[(size_t)((g * 2 + pp) * 128 +
                                                       t * 16 + l15) * 20 + quad * 4];
        o[u][t] += part;
      }
    }
    __syncthreads();
    if (pp == 1) {
#pragma unroll
      for (int t = 0; t < 8; ++t)
        *(floatx4*)&obuf[(size_t)(g * 128 + t * 16 + l15) * 20 + quad * 4] = o[u][t];
    }
    __syncthreads();
    if (pp == 0) {
      float lt = 0.f;
#pragma unroll
      for (int j = 0; j < 4; ++j) lt += lbuf[((g * 4 + j) * 2 + u) * 16 + l15];
      float inv[4];
#pragma unroll
      for (int r = 0; r < 4; ++r) inv[r] = 1.f / __shfl(lt, quad * 4 + r);
#pragma unroll
      for (int t = 0; t < 8; ++t) {
        floatx4 part = *(const floatx4*)&obuf[(size_t)(g * 128 + t * 16 + l15) * 20 +
                                              quad * 4];
#pragma unroll
        for (int r = 0; r < 4; ++r) {
          int rowq = qrow + u * 16 + quad * 4 + r;
          ctx[(size_t)rowq * E_DIM + h * D_HEAD + t * 16 + l15] =
              (_Float16)((o[u][t][r] + part[r]) * inv[r]);
        }
      }
    }
  }
}

// ---------------------------------------------------------------------------
extern "C" void kernel_launch(void* const* d_in, const int* in_sizes, int n_in,
                              void* d_out, int out_size, void* d_ws, size_t ws_size,
                              hipStream_t stream) {
  const float* x          = (const float*)d_in[0];
  const float* bias_mat   = (const float*)d_in[1];
  const float* in_proj_w  = (const float*)d_in[2];
  const float* in_proj_b  = (const float*)d_in[3];
  const float* out_proj_w = (const float*)d_in[4];
  const float* out_proj_b = (const float*)d_in[5];
  float* out = (float*)d_out;

  _Float16* x16 = (_Float16*)d_ws;                         // L*E
  _Float16* w1  = x16 + (size_t)L_SEQ * E_DIM;             // 3E*E
  _Float16* w2  = w1 + (size_t)3 * E_DIM * E_DIM;          // E*E
  _Float16* qk  = w2 + (size_t)E_DIM * E_DIM;              // L*2E
  _Float16* vt  = qk + (size_t)L_SEQ * 2 * E_DIM;          // E*L
  _Float16* ctx = vt + (size_t)E_DIM * L_SEQ;              // L*E

  dim3 blk(256);
  const int nx = L_SEQ * E_DIM, nw1 = 3 * E_DIM * E_DIM, nw2 = E_DIM * E_DIM;

  cvt3_f32_f16<<<(nx + nw1 + nw2) / 2048, blk, 0, stream>>>(
      x, x16, nx, in_proj_w, w1, nw1, out_proj_w, w2, nw2);

  gemm_mfma<128, 128, 2, 2, 1><<<dim3(3 * E_DIM / 128, L_SEQ / 128), blk, 0, stream>>>(
      x16, w1, in_proj_b, nullptr, qk, vt, L_SEQ, 3 * E_DIM, E_DIM);

  attn_mfma<<<dim3(H_NUM, L_SEQ / 128), dim3(1024), 0, stream>>>(qk, vt, bias_mat,
                                                                 ctx);

  gemm_mfma<128, 64, 4, 1, 0><<<dim3(E_DIM / 64, L_SEQ / 128), blk, 0, stream>>>(
      ctx, w2, out_proj_b, out, nullptr, nullptr, L_SEQ, E_DIM, E_DIM);
}

// Round 3
// 343.569 us; speedup vs baseline: 1.1627x; 1.1627x over previous
//
#include <hip/hip_runtime.h>
#include <math.h>

#define L_SEQ 2048
#define E_DIM 2048
#define H_NUM 16
#define D_HEAD 128

typedef __attribute__((ext_vector_type(8))) _Float16 half8;
typedef __attribute__((ext_vector_type(4))) _Float16 half4;
typedef __attribute__((ext_vector_type(4))) float floatx4;

// async global->LDS, 16B per lane. LDS dest is wave-uniform base + lane*16.
static __device__ __forceinline__ void gload16(const void* g, void* lds) {
  __builtin_amdgcn_global_load_lds(
      (const __attribute__((address_space(1))) void*)g,
      (__attribute__((address_space(3))) void*)lds, 16, 0, 0);
}

// ---------------------------------------------------------------------------
// Fused fp32 -> fp16 conversion of x, in_proj_w, out_proj_w (one launch).
// ---------------------------------------------------------------------------
__global__ __launch_bounds__(256)
void cvt3_f32_f16(const float* __restrict__ a, _Float16* __restrict__ oa, int na,
                  const float* __restrict__ b, _Float16* __restrict__ ob, int nb,
                  const float* __restrict__ c, _Float16* __restrict__ oc, int nc) {
  int i = (blockIdx.x * 256 + threadIdx.x) * 8;
  const float* src;
  _Float16* dst;
  if (i < na) {
    src = a + i; dst = oa + i;
  } else if (i < na + nb) {
    src = b + (i - na); dst = ob + (i - na);
  } else if (i < na + nb + nc) {
    src = c + (i - na - nb); dst = oc + (i - na - nb);
  } else {
    return;
  }
  float4 p = *(const float4*)src;
  float4 q = *(const float4*)(src + 4);
  half8 h = {(_Float16)p.x, (_Float16)p.y, (_Float16)p.z, (_Float16)p.w,
             (_Float16)q.x, (_Float16)q.y, (_Float16)q.z, (_Float16)q.w};
  *(half8*)dst = h;
}

// ---------------------------------------------------------------------------
// MFMA GEMM (NT) v2 (R7-verified): unchanged this round.
// ---------------------------------------------------------------------------
template <int TM, int TN, int WR, int WC, int EPI>
__global__ __launch_bounds__(256)
void gemm_mfma(const _Float16* __restrict__ A, const _Float16* __restrict__ B,
               const float* __restrict__ bias, float* __restrict__ C,
               _Float16* __restrict__ qk, _Float16* __restrict__ vt,
               int M, int N, int K) {
  constexpr int RT = TM / (16 * WR);
  constexpr int CT = TN / (16 * WC);
  constexpr int ACH = TM / 8;
  constexpr int NCH = (TM + TN) / 32;

  __shared__ _Float16 As[2][TM * 64];
  __shared__ _Float16 Bs[2][TN * 64];

  const int tid = threadIdx.x;
  const int wave = tid >> 6, lane = tid & 63;
  const int l15 = lane & 15, quad = lane >> 4;
  const int wr = wave / WC, wc = wave % WC;
  const int row0 = blockIdx.y * TM, col0 = blockIdx.x * TN;

  const int srow = lane >> 3;
  const int gc = (lane & 7) ^ srow;

  auto stage = [&](int buf, int k0) {
#pragma unroll
    for (int c = 0; c < NCH; ++c) {
      int chunk = wave * NCH + c;
      if (chunk < ACH) {
        int row = chunk * 8 + srow;
        gload16((const char*)(A + (size_t)(row0 + row) * K + k0) + gc * 16,
                (char*)&As[buf][0] + chunk * 1024);
      } else {
        int bch = chunk - ACH;
        int row = bch * 8 + srow;
        gload16((const char*)(B + (size_t)(col0 + row) * K + k0) + gc * 16,
                (char*)&Bs[buf][0] + bch * 1024);
      }
    }
  };

  floatx4 acc[RT][CT];
#pragma unroll
  for (int i = 0; i < RT; ++i)
#pragma unroll
    for (int j = 0; j < CT; ++j) acc[i][j] = (floatx4){0.f, 0.f, 0.f, 0.f};

  const int niter = K / 64;
  stage(0, 0);

  for (int it = 0; it < niter; ++it) {
    const int cur = it & 1;
    __syncthreads();
    if (it + 1 < niter) stage(cur ^ 1, (it + 1) * 64);

#pragma unroll
    for (int ks = 0; ks < 2; ++ks) {
      half8 af[RT], bf[CT];
#pragma unroll
      for (int t = 0; t < RT; ++t) {
        int r = wr * (16 * RT) + t * 16 + l15;
        af[t] = *(const half8*)&As[cur][r * 64 + (((ks * 4 + quad) ^ (r & 7)) * 8)];
      }
#pragma unroll
      for (int t = 0; t < CT; ++t) {
        int r = wc * (16 * CT) + t * 16 + l15;
        bf[t] = *(const half8*)&Bs[cur][r * 64 + (((ks * 4 + quad) ^ (r & 7)) * 8)];
      }
#pragma unroll
      for (int tr = 0; tr < RT; ++tr)
#pragma unroll
        for (int tc = 0; tc < CT; ++tc)
          acc[tr][tc] = __builtin_amdgcn_mfma_f32_16x16x32_f16(
              af[tr], bf[tc], acc[tr][tc], 0, 0, 0);
    }
  }

  const int crow = row0 + wr * (16 * RT);
  const int ccol = col0 + wc * (16 * CT);

  if (EPI == 0) {
#pragma unroll
    for (int tc = 0; tc < CT; ++tc) {
      int col = ccol + tc * 16 + l15;
      float bb = bias[col];
#pragma unroll
      for (int tr = 0; tr < RT; ++tr)
#pragma unroll
        for (int r = 0; r < 4; ++r)
          C[(size_t)(crow + tr * 16 + quad * 4 + r) * N + col] =
              acc[tr][tc][r] + bb;
    }
  } else if (col0 < 2 * E_DIM) {
#pragma unroll
    for (int tc = 0; tc < CT; ++tc) {
      int col = ccol + tc * 16 + l15;
      float bb = bias[col];
#pragma unroll
      for (int tr = 0; tr < RT; ++tr)
#pragma unroll
        for (int r = 0; r < 4; ++r)
          qk[(size_t)(crow + tr * 16 + quad * 4 + r) * (2 * E_DIM) + col] =
              (_Float16)(acc[tr][tc][r] + bb);
    }
  } else {
#pragma unroll
    for (int tc = 0; tc < CT; ++tc) {
      int col = ccol + tc * 16 + l15;
      float bb = bias[col];
      int vrow = col - 2 * E_DIM;
#pragma unroll
      for (int tr = 0; tr < RT; ++tr) {
        int rbase = crow + tr * 16 + quad * 4;
        half4 h = {(_Float16)(acc[tr][tc][0] + bb), (_Float16)(acc[tr][tc][1] + bb),
                   (_Float16)(acc[tr][tc][2] + bb), (_Float16)(acc[tr][tc][3] + bb)};
        *(half4*)&vt[(size_t)vrow * L_SEQ + rbase] = h;
      }
    }
  }
}

// ---------------------------------------------------------------------------
// MFMA flash attention v8 — occupancy via MORE BLOCKS, not bigger blocks.
// (v7 post-mortem: __launch_bounds__ 2nd arg = min BLOCKS/CU (CUDA sem);
//  (1024,4) -> 64-VGPR cap -> spill disaster. v6's reg set fits 128 (120).)
// Grid (H, L/64) = 512 blocks, 512 thr = 8 waves, LDS 64KB -> 2 blocks/CU
// -> 4 waves/SIMD (2x v6's latency hiding, same per-CU LDS traffic).
// Wave (g = wave>>2 in {0,1}, pp = wave&3): 32 q-rows, key-tiles of parity
// pp (KVBLK=16; gen=64 keys; 32 supersteps, double-buffered).
//  - K slots 8 x [16 key][128 d] (4KB), chunk swizzle cc ^ (row&7)
//  - V slots 8 x [128 d][16 key] (4KB), chunk swizzle cc ^ ((d>>2)&1)
//    both staged via global_load_lds with pre-swizzled global source.
//  - PV uses mfma_f32_16x16x16f16: S^T fragment layout IS the x16 A-fragment
//    layout, so P never touches LDS. 4-parity merge at end (plain sums).
// ---------------------------------------------------------------------------
__global__ __launch_bounds__(512, 2)
void attn_mfma(const _Float16* __restrict__ qk, const _Float16* __restrict__ vt,
               const float* __restrict__ bias, _Float16* __restrict__ ctx) {
  const int h = blockIdx.x;
  const int q0 = blockIdx.y * 64;
  const int tid = threadIdx.x;
  const int wave = tid >> 6;
  const int lane = tid & 63;
  const int l15 = lane & 15;
  const int quad = lane >> 4;
  const int g = wave >> 2;   // row-group: rows q0 + g*32 .. +31
  const int pp = wave & 3;   // key-tile parity (mod 4)

  __shared__ __align__(16) char smem[65536];
  char* const ksmem = smem;          // 8 slots x 4KB: [16 key][128 d]
  char* const vsmem = smem + 32768;  // 8 slots x 4KB: [128 d][16 key]

  const int qrow = q0 + g * 32;

  // Q fragments (B-operand of S^T = K*Q^T): qa[u][ks]
  half8 qa[2][4];
#pragma unroll
  for (int u = 0; u < 2; ++u) {
    const _Float16* qp =
        qk + (size_t)(qrow + u * 16 + l15) * (2 * E_DIM) + h * D_HEAD + quad * 8;
#pragma unroll
    for (int ks = 0; ks < 4; ++ks) qa[u][ks] = *(const half8*)(qp + ks * 32);
  }

  float l_acc[2] = {0.f, 0.f};
  floatx4 o[2][8];
#pragma unroll
  for (int u = 0; u < 2; ++u)
#pragma unroll
    for (int t = 0; t < 8; ++t) o[u][t] = (floatx4){0.f, 0.f, 0.f, 0.f};

  const float scale = 0.088388347648318447f;  // 1/sqrt(128)

  // stage one 64-key generation (4 tiles of 16) into slots sb..sb+3.
  // 2048 16B-chunks (K 1024 + V 1024) over 512 threads -> 4 each.
  auto stage_gen = [&](int kt2, int sb) {
#pragma unroll
    for (int c = 0; c < 4; ++c) {
      int mb = c * 512 + (tid & ~63);  // wave-uniform chunk base
      int m = mb + (tid & 63);
      if (mb < 1024) {  // K region
        int sub = mb >> 8;
        int idx = m & 255, idx0 = mb & 255;
        int row = idx >> 4, cc = idx & 15;
        gload16(qk + (size_t)(kt2 + sub * 16 + row) * (2 * E_DIM) + E_DIM +
                    h * D_HEAD + ((cc ^ (row & 7)) * 8),
                ksmem + (sb + sub) * 4096 + idx0 * 16);
      } else {  // V region
        int mb2 = mb - 1024;
        int sub = mb2 >> 8;
        int idx = (m - 1024) & 255, idx0 = mb2 & 255;
        int row = idx >> 1, cc = idx & 1;
        gload16(vt + (size_t)(h * D_HEAD + row) * L_SEQ + kt2 + sub * 16 +
                    ((cc ^ ((row >> 2) & 1)) * 8),
                vsmem + (sb + sub) * 4096 + idx0 * 16);
      }
    }
  };

  stage_gen(0, 0);

#pragma unroll 2
  for (int s = 0; s < 32; ++s) {
    const int kt = s * 64 + pp * 16;         // this wave's key-tile base
    const int slot = (s & 1) * 4 + pp;
    __syncthreads();  // gen-s staging drained; gen-(s+1) slots' readers done

    if (s < 31) stage_gen((s + 1) * 64, ((s + 1) & 1) * 4);

    // ---- S^T = K*Q^T : col=l15=q, row=quad*4+r=key ----
    const char* ksb = ksmem + slot * 4096;
    floatx4 st[2];
    st[0] = (floatx4){0.f, 0.f, 0.f, 0.f};
    st[1] = (floatx4){0.f, 0.f, 0.f, 0.f};
#pragma unroll
    for (int ks = 0; ks < 4; ++ks) {
      half8 kf = *(const half8*)(ksb + l15 * 256 +
                                 (((ks * 4 + quad) ^ (l15 & 7)) * 16));
      st[0] = __builtin_amdgcn_mfma_f32_16x16x32_f16(kf, qa[0][ks], st[0], 0, 0, 0);
      st[1] = __builtin_amdgcn_mfma_f32_16x16x32_f16(kf, qa[1][ks], st[1], 0, 0, 0);
    }

    // ---- softmax (no max subtraction); hp = x16 A-fragment directly ----
    half4 hp[2];
#pragma unroll
    for (int u = 0; u < 2; ++u) {
      floatx4 bq = *(const floatx4*)&bias[(size_t)(qrow + u * 16 + l15) * L_SEQ +
                                          kt + quad * 4];
      float p0 = __expf(fmaf(st[u][0], scale, bq[0]));
      float p1 = __expf(fmaf(st[u][1], scale, bq[1]));
      float p2 = __expf(fmaf(st[u][2], scale, bq[2]));
      float p3 = __expf(fmaf(st[u][3], scale, bq[3]));
      float ls = (p0 + p1) + (p2 + p3);
      ls += __shfl_xor(ls, 16);
      ls += __shfl_xor(ls, 32);
      l_acc[u] += ls;
      hp[u] = (half4){(_Float16)p0, (_Float16)p1, (_Float16)p2, (_Float16)p3};
    }

    // ---- O += P V via x16 MFMA (P stays in registers) ----
    const char* vsb = vsmem + slot * 4096;
#pragma unroll
    for (int td = 0; td < 8; ++td) {
      int row = td * 16 + l15;
      half4 vf = *(const half4*)(vsb + row * 32 +
                                 ((((quad >> 1) ^ ((row >> 2) & 1)) * 16) +
                                  (quad & 1) * 8));
      o[0][td] = __builtin_amdgcn_mfma_f32_16x16x16f16(hp[0], vf, o[0][td], 0, 0, 0);
      o[1][td] = __builtin_amdgcn_mfma_f32_16x16x16f16(hp[1], vf, o[1][td], 0, 0, 0);
    }
  }

  // ---- 4-parity merge (plain sums; no-max softmax) + epilogue ----
  // obuf: [4 slot][128 col][20 pad] floats = 40KB; lbuf after it.
  float* obuf = (float*)smem;
  float* lbuf = (float*)(smem + 40960);
  __syncthreads();  // all K/V slot readers done before LDS reuse
  if (quad == 0) {
    lbuf[((g * 4 + pp) * 2 + 0) * 16 + l15] = l_acc[0];
    lbuf[((g * 4 + pp) * 2 + 1) * 16 + l15] = l_acc[1];
  }

#pragma unroll
  for (int u = 0; u < 2; ++u) {
    __syncthreads();
    if (pp >= 2) {
#pragma unroll
      for (int t = 0; t < 8; ++t)
        *(floatx4*)&obuf[(size_t)((g * 2 + (pp - 2)) * 128 + t * 16 + l15) * 20 +
                         quad * 4] = o[u][t];
    }
    __syncthreads();
    if (pp < 2) {
#pragma unroll
      for (int t = 0; t < 8; ++t) {
        floatx4 part = *(const floatx4*)&obuf[(size_t)((g * 2 + pp) * 128 +
                                                       t * 16 + l15) * 20 + quad * 4];
        o[u][t] += part;
      }
    }
    __syncthreads();
    if (pp == 1) {
#pragma unroll
      for (int t = 0; t < 8; ++t)
        *(floatx4*)&obuf[(size_t)(g * 128 + t * 16 + l15) * 20 + quad * 4] = o[u][t];
    }
    __syncthreads();
    if (pp == 0) {
      float lt = 0.f;
#pragma unroll
      for (int j = 0; j < 4; ++j) lt += lbuf[((g * 4 + j) * 2 + u) * 16 + l15];
      float inv[4];
#pragma unroll
      for (int r = 0; r < 4; ++r) inv[r] = 1.f / __shfl(lt, quad * 4 + r);
#pragma unroll
      for (int t = 0; t < 8; ++t) {
        floatx4 part = *(const floatx4*)&obuf[(size_t)(g * 128 + t * 16 + l15) * 20 +
                                              quad * 4];
#pragma unroll
        for (int r = 0; r < 4; ++r) {
          int rowq = qrow + u * 16 + quad * 4 + r;
          ctx[(size_t)rowq * E_DIM + h * D_HEAD + t * 16 + l15] =
              (_Float16)((o[u][t][r] + part[r]) * inv[r]);
        }
      }
    }
  }
}

// ---------------------------------------------------------------------------
extern "C" void kernel_launch(void* const* d_in, const int* in_sizes, int n_in,
                              void* d_out, int out_size, void* d_ws, size_t ws_size,
                              hipStream_t stream) {
  const float* x          = (const float*)d_in[0];
  const float* bias_mat   = (const float*)d_in[1];
  const float* in_proj_w  = (const float*)d_in[2];
  const float* in_proj_b  = (const float*)d_in[3];
  const float* out_proj_w = (const float*)d_in[4];
  const float* out_proj_b = (const float*)d_in[5];
  float* out = (float*)d_out;

  _Float16* x16 = (_Float16*)d_ws;                         // L*E
  _Float16* w1  = x16 + (size_t)L_SEQ * E_DIM;             // 3E*E
  _Float16* w2  = w1 + (size_t)3 * E_DIM * E_DIM;          // E*E
  _Float16* qk  = w2 + (size_t)E_DIM * E_DIM;              // L*2E
  _Float16* vt  = qk + (size_t)L_SEQ * 2 * E_DIM;          // E*L
  _Float16* ctx = vt + (size_t)E_DIM * L_SEQ;              // L*E

  dim3 blk(256);
  const int nx = L_SEQ * E_DIM, nw1 = 3 * E_DIM * E_DIM, nw2 = E_DIM * E_DIM;

  cvt3_f32_f16<<<(nx + nw1 + nw2) / 2048, blk, 0, stream>>>(
      x, x16, nx, in_proj_w, w1, nw1, out_proj_w, w2, nw2);

  gemm_mfma<128, 128, 2, 2, 1><<<dim3(3 * E_DIM / 128, L_SEQ / 128), blk, 0, stream>>>(
      x16, w1, in_proj_b, nullptr, qk, vt, L_SEQ, 3 * E_DIM, E_DIM);

  attn_mfma<<<dim3(H_NUM, L_SEQ / 64), dim3(512), 0, stream>>>(qk, vt, bias_mat,
                                                               ctx);

  gemm_mfma<128, 64, 4, 1, 0><<<dim3(E_DIM / 64, L_SEQ / 128), blk, 0, stream>>>(
      ctx, w2, out_proj_b, out, nullptr, nullptr, L_SEQ, E_DIM, E_DIM);
}

// Round 4
// 293.365 us; speedup vs baseline: 1.3616x; 1.1711x over previous
//
#include <hip/hip_runtime.h>
#include <math.h>

#define L_SEQ 2048
#define E_DIM 2048
#define H_NUM 16
#define D_HEAD 128

typedef __attribute__((ext_vector_type(8))) _Float16 half8;
typedef __attribute__((ext_vector_type(4))) _Float16 half4;
typedef __attribute__((ext_vector_type(4))) float floatx4;

// async global->LDS, 16B per lane. LDS dest is wave-uniform base + lane*16.
static __device__ __forceinline__ void gload16(const void* g, void* lds) {
  __builtin_amdgcn_global_load_lds(
      (const __attribute__((address_space(1))) void*)g,
      (__attribute__((address_space(3))) void*)lds, 16, 0, 0);
}

// ---------------------------------------------------------------------------
// Fused fp32 -> fp16 conversion of x, in_proj_w, out_proj_w (one launch).
// ---------------------------------------------------------------------------
__global__ __launch_bounds__(256)
void cvt3_f32_f16(const float* __restrict__ a, _Float16* __restrict__ oa, int na,
                  const float* __restrict__ b, _Float16* __restrict__ ob, int nb,
                  const float* __restrict__ c, _Float16* __restrict__ oc, int nc) {
  int i = (blockIdx.x * 256 + threadIdx.x) * 8;
  const float* src;
  _Float16* dst;
  if (i < na) {
    src = a + i; dst = oa + i;
  } else if (i < na + nb) {
    src = b + (i - na); dst = ob + (i - na);
  } else if (i < na + nb + nc) {
    src = c + (i - na - nb); dst = oc + (i - na - nb);
  } else {
    return;
  }
  float4 p = *(const float4*)src;
  float4 q = *(const float4*)(src + 4);
  half8 h = {(_Float16)p.x, (_Float16)p.y, (_Float16)p.z, (_Float16)p.w,
             (_Float16)q.x, (_Float16)q.y, (_Float16)q.z, (_Float16)q.w};
  *(half8*)dst = h;
}

// ---------------------------------------------------------------------------
// MFMA GEMM (NT) v2 (R7-verified): double-buffered LDS, ONE barrier per
// K-iter, async global_load_lds staging, fp16 in, fp32 acc. BK=64.
// ---------------------------------------------------------------------------
template <int TM, int TN, int WR, int WC, int EPI>
__global__ __launch_bounds__(256)
void gemm_mfma(const _Float16* __restrict__ A, const _Float16* __restrict__ B,
               const float* __restrict__ bias, float* __restrict__ C,
               _Float16* __restrict__ qk, _Float16* __restrict__ vt,
               int M, int N, int K) {
  constexpr int RT = TM / (16 * WR);
  constexpr int CT = TN / (16 * WC);
  constexpr int ACH = TM / 8;
  constexpr int NCH = (TM + TN) / 32;

  __shared__ _Float16 As[2][TM * 64];
  __shared__ _Float16 Bs[2][TN * 64];

  const int tid = threadIdx.x;
  const int wave = tid >> 6, lane = tid & 63;
  const int l15 = lane & 15, quad = lane >> 4;
  const int wr = wave / WC, wc = wave % WC;
  const int row0 = blockIdx.y * TM, col0 = blockIdx.x * TN;

  const int srow = lane >> 3;
  const int gc = (lane & 7) ^ srow;

  auto stage = [&](int buf, int k0) {
#pragma unroll
    for (int c = 0; c < NCH; ++c) {
      int chunk = wave * NCH + c;
      if (chunk < ACH) {
        int row = chunk * 8 + srow;
        gload16((const char*)(A + (size_t)(row0 + row) * K + k0) + gc * 16,
                (char*)&As[buf][0] + chunk * 1024);
      } else {
        int bch = chunk - ACH;
        int row = bch * 8 + srow;
        gload16((const char*)(B + (size_t)(col0 + row) * K + k0) + gc * 16,
                (char*)&Bs[buf][0] + bch * 1024);
      }
    }
  };

  floatx4 acc[RT][CT];
#pragma unroll
  for (int i = 0; i < RT; ++i)
#pragma unroll
    for (int j = 0; j < CT; ++j) acc[i][j] = (floatx4){0.f, 0.f, 0.f, 0.f};

  const int niter = K / 64;
  stage(0, 0);

  for (int it = 0; it < niter; ++it) {
    const int cur = it & 1;
    __syncthreads();  // buf[cur] loads landed during previous compute
    if (it + 1 < niter) stage(cur ^ 1, (it + 1) * 64);

#pragma unroll
    for (int ks = 0; ks < 2; ++ks) {
      half8 af[RT], bf[CT];
#pragma unroll
      for (int t = 0; t < RT; ++t) {
        int r = wr * (16 * RT) + t * 16 + l15;
        af[t] = *(const half8*)&As[cur][r * 64 + (((ks * 4 + quad) ^ (r & 7)) * 8)];
      }
#pragma unroll
      for (int t = 0; t < CT; ++t) {
        int r = wc * (16 * CT) + t * 16 + l15;
        bf[t] = *(const half8*)&Bs[cur][r * 64 + (((ks * 4 + quad) ^ (r & 7)) * 8)];
      }
#pragma unroll
      for (int tr = 0; tr < RT; ++tr)
#pragma unroll
        for (int tc = 0; tc < CT; ++tc)
          acc[tr][tc] = __builtin_amdgcn_mfma_f32_16x16x32_f16(
              af[tr], bf[tc], acc[tr][tc], 0, 0, 0);
    }
  }

  const int crow = row0 + wr * (16 * RT);
  const int ccol = col0 + wc * (16 * CT);

  if (EPI == 0) {
#pragma unroll
    for (int tc = 0; tc < CT; ++tc) {
      int col = ccol + tc * 16 + l15;
      float bb = bias[col];
#pragma unroll
      for (int tr = 0; tr < RT; ++tr)
#pragma unroll
        for (int r = 0; r < 4; ++r)
          C[(size_t)(crow + tr * 16 + quad * 4 + r) * N + col] =
              acc[tr][tc][r] + bb;
    }
  } else if (col0 < 2 * E_DIM) {
#pragma unroll
    for (int tc = 0; tc < CT; ++tc) {
      int col = ccol + tc * 16 + l15;
      float bb = bias[col];
#pragma unroll
      for (int tr = 0; tr < RT; ++tr)
#pragma unroll
        for (int r = 0; r < 4; ++r)
          qk[(size_t)(crow + tr * 16 + quad * 4 + r) * (2 * E_DIM) + col] =
              (_Float16)(acc[tr][tc][r] + bb);
    }
  } else {
#pragma unroll
    for (int tc = 0; tc < CT; ++tc) {
      int col = ccol + tc * 16 + l15;
      float bb = bias[col];
      int vrow = col - 2 * E_DIM;
#pragma unroll
      for (int tr = 0; tr < RT; ++tr) {
        int rbase = crow + tr * 16 + quad * 4;
        half4 h = {(_Float16)(acc[tr][tc][0] + bb), (_Float16)(acc[tr][tc][1] + bb),
                   (_Float16)(acc[tr][tc][2] + bb), (_Float16)(acc[tr][tc][3] + bb)};
        *(half4*)&vt[(size_t)vrow * L_SEQ + rbase] = h;
      }
    }
  }
}

// ---------------------------------------------------------------------------
// MFMA flash attention v9 = v5 (proven 70us) + reg-resident P.
// Grid (H, L/128) = 256 blocks, 512 thr = 8 waves. Wave owns 16 q-rows.
// Bc=64 keys/iter, 32 iters, double-buffered K/V LDS, one barrier/iter,
// reg-prefetch of next tile + bias, S^T=K*Q^T trick, no-max softmax.
// v9 diff vs v5 (ONLY change): Ps LDS buffer eliminated — the S^T fragment
// (m=l15=q, k=quad*4+r=key) is exactly the x16 MFMA A-fragment, so PV uses
// mfma_f32_16x16x16_f16 with P in registers (removes 4 ds_write + 2 ds_read
// + one lgkmcnt sync per wave-iter; LDS 90KB -> 70KB).
// ---------------------------------------------------------------------------
__global__ __launch_bounds__(512, 2)
void attn_mfma(const _Float16* __restrict__ qk, const _Float16* __restrict__ vt,
               const float* __restrict__ bias, _Float16* __restrict__ ctx) {
  const int h = blockIdx.x;
  const int q0 = blockIdx.y * 128;
  const int tid = threadIdx.x;
  const int wave = tid >> 6;
  const int lane = tid & 63;
  const int l15 = lane & 15;
  const int quad = lane >> 4;

  __shared__ _Float16 Ks[2][64][136];   // [buf][key][d]
  __shared__ _Float16 Vst[2][128][72];  // [buf][d][key]

  // Q fragments (B-operand: B[k=quad*8+j][n=l15=q]):
  half8 qa[4];
  {
    const _Float16* qp = qk + (size_t)(q0 + wave * 16 + l15) * (2 * E_DIM) +
                         h * D_HEAD + quad * 8;
#pragma unroll
    for (int ks = 0; ks < 4; ++ks) qa[ks] = *(const half8*)(qp + ks * 32);
  }

  float l_i = 0.f;
  floatx4 o[8];
#pragma unroll
  for (int t = 0; t < 8; ++t) o[t] = (floatx4){0.f, 0.f, 0.f, 0.f};

  const float scale = 0.088388347648318447f;  // 1/sqrt(128)

  // staging (512 threads, 2 chunks each of K and V):
  half8 kreg[2], vreg[2];
  floatx4 bcur[4], bnxt[4];
#pragma unroll
  for (int c = 0; c < 2; ++c) {
    int m = c * 512 + tid;
    kreg[c] = *(const half8*)(qk + (size_t)(m >> 4) * (2 * E_DIM) + E_DIM +
                              h * D_HEAD + (m & 15) * 8);
    vreg[c] = *(const half8*)(vt + (size_t)(h * D_HEAD + (m >> 3)) * L_SEQ +
                              (m & 7) * 8);
  }
#pragma unroll
  for (int t = 0; t < 4; ++t)
    bcur[t] = *(const floatx4*)&bias[(size_t)(q0 + wave * 16 + l15) * L_SEQ +
                                    16 * t + quad * 4];
#pragma unroll
  for (int c = 0; c < 2; ++c) {
    int m = c * 512 + tid;
    *(half8*)&Ks[0][m >> 4][(m & 15) * 8] = kreg[c];
    *(half8*)&Vst[0][m >> 3][(m & 7) * 8] = vreg[c];
  }

#pragma unroll 2
  for (int it = 0; it < 32; ++it) {
    const int cur = it & 1, nxt = cur ^ 1;
    const int kt = it * 64;
    __syncthreads();  // buf[cur] writes visible; buf[nxt] readers (it-1) done

    if (it < 31) {
#pragma unroll
      for (int c = 0; c < 2; ++c) {
        int m = c * 512 + tid;
        kreg[c] = *(const half8*)(qk + (size_t)(kt + 64 + (m >> 4)) * (2 * E_DIM) +
                                  E_DIM + h * D_HEAD + (m & 15) * 8);
        vreg[c] = *(const half8*)(vt + (size_t)(h * D_HEAD + (m >> 3)) * L_SEQ +
                                  kt + 64 + (m & 7) * 8);
      }
#pragma unroll
      for (int t = 0; t < 4; ++t)
        bnxt[t] = *(const floatx4*)&bias[(size_t)(q0 + wave * 16 + l15) * L_SEQ +
                                         kt + 64 + 16 * t + quad * 4];
    }

    // ---- S^T = K Q^T : col=l15=q, row=quad*4+reg=key(within 16t) ----
    floatx4 st[4];
#pragma unroll
    for (int t = 0; t < 4; ++t) st[t] = (floatx4){0.f, 0.f, 0.f, 0.f};
#pragma unroll
    for (int ks = 0; ks < 4; ++ks)
#pragma unroll
      for (int t = 0; t < 4; ++t) {
        half8 kf = *(const half8*)&Ks[cur][16 * t + l15][ks * 32 + quad * 8];
        st[t] = __builtin_amdgcn_mfma_f32_16x16x32_f16(kf, qa[ks], st[t], 0, 0, 0);
      }

    // ---- softmax (no max subtraction); hp[t] = x16 A-fragment directly ----
    half4 hp[4];
    {
      float ls = 0.f;
#pragma unroll
      for (int t = 0; t < 4; ++t) {
        float p0 = __expf(fmaf(st[t][0], scale, bcur[t][0]));
        float p1 = __expf(fmaf(st[t][1], scale, bcur[t][1]));
        float p2 = __expf(fmaf(st[t][2], scale, bcur[t][2]));
        float p3 = __expf(fmaf(st[t][3], scale, bcur[t][3]));
        ls += (p0 + p1) + (p2 + p3);
        hp[t] = (half4){(_Float16)p0, (_Float16)p1, (_Float16)p2, (_Float16)p3};
      }
      ls += __shfl_xor(ls, 16);
      ls += __shfl_xor(ls, 32);
      l_i += ls;
    }

    // ---- O += P V via x16 MFMA (P stays in registers; A-frag k=quad*4+r) ----
#pragma unroll
    for (int t = 0; t < 8; ++t)
#pragma unroll
      for (int tk = 0; tk < 4; ++tk) {
        half4 vf = *(const half4*)&Vst[cur][16 * t + l15][tk * 16 + quad * 4];
        o[t] = __builtin_amdgcn_mfma_f32_16x16x16f16(hp[tk], vf, o[t], 0, 0, 0);
      }

    if (it < 31) {
#pragma unroll
      for (int c = 0; c < 2; ++c) {
        int m = c * 512 + tid;
        *(half8*)&Ks[nxt][m >> 4][(m & 15) * 8] = kreg[c];
        *(half8*)&Vst[nxt][m >> 3][(m & 7) * 8] = vreg[c];
      }
#pragma unroll
      for (int t = 0; t < 4; ++t) bcur[t] = bnxt[t];
    }
  }

  // ---- epilogue: ctx = O / l. l lives at lane l15=q; o rows are quad*4+r ----
  float inv[4];
#pragma unroll
  for (int r = 0; r < 4; ++r) inv[r] = 1.f / __shfl(l_i, quad * 4 + r);
#pragma unroll
  for (int t = 0; t < 8; ++t)
#pragma unroll
    for (int r = 0; r < 4; ++r) {
      int row = q0 + wave * 16 + quad * 4 + r;
      ctx[(size_t)row * E_DIM + h * D_HEAD + 16 * t + l15] =
          (_Float16)(o[t][r] * inv[r]);
    }
}

// ---------------------------------------------------------------------------
extern "C" void kernel_launch(void* const* d_in, const int* in_sizes, int n_in,
                              void* d_out, int out_size, void* d_ws, size_t ws_size,
                              hipStream_t stream) {
  const float* x          = (const float*)d_in[0];
  const float* bias_mat   = (const float*)d_in[1];
  const float* in_proj_w  = (const float*)d_in[2];
  const float* in_proj_b  = (const float*)d_in[3];
  const float* out_proj_w = (const float*)d_in[4];
  const float* out_proj_b = (const float*)d_in[5];
  float* out = (float*)d_out;

  _Float16* x16 = (_Float16*)d_ws;                         // L*E
  _Float16* w1  = x16 + (size_t)L_SEQ * E_DIM;             // 3E*E
  _Float16* w2  = w1 + (size_t)3 * E_DIM * E_DIM;          // E*E
  _Float16* qk  = w2 + (size_t)E_DIM * E_DIM;              // L*2E
  _Float16* vt  = qk + (size_t)L_SEQ * 2 * E_DIM;          // E*L
  _Float16* ctx = vt + (size_t)E_DIM * L_SEQ;              // L*E

  dim3 blk(256);
  const int nx = L_SEQ * E_DIM, nw1 = 3 * E_DIM * E_DIM, nw2 = E_DIM * E_DIM;

  cvt3_f32_f16<<<(nx + nw1 + nw2) / 2048, blk, 0, stream>>>(
      x, x16, nx, in_proj_w, w1, nw1, out_proj_w, w2, nw2);

  gemm_mfma<128, 128, 2, 2, 1><<<dim3(3 * E_DIM / 128, L_SEQ / 128), blk, 0, stream>>>(
      x16, w1, in_proj_b, nullptr, qk, vt, L_SEQ, 3 * E_DIM, E_DIM);

  attn_mfma<<<dim3(H_NUM, L_SEQ / 128), dim3(512), 0, stream>>>(qk, vt, bias_mat,
                                                                ctx);

  gemm_mfma<128, 64, 4, 1, 0><<<dim3(E_DIM / 64, L_SEQ / 128), blk, 0, stream>>>(
      ctx, w2, out_proj_b, out, nullptr, nullptr, L_SEQ, E_DIM, E_DIM);
}

// Round 5
// 284.548 us; speedup vs baseline: 1.4038x; 1.0310x over previous
//
#include <hip/hip_runtime.h>
#include <math.h>

#define L_SEQ 2048
#define E_DIM 2048
#define H_NUM 16
#define D_HEAD 128

typedef __attribute__((ext_vector_type(8))) _Float16 half8;
typedef __attribute__((ext_vector_type(4))) _Float16 half4;
typedef __attribute__((ext_vector_type(4))) float floatx4;

// async global->LDS, 16B per lane. LDS dest is wave-uniform base + lane*16.
static __device__ __forceinline__ void gload16(const void* g, void* lds) {
  __builtin_amdgcn_global_load_lds(
      (const __attribute__((address_space(1))) void*)g,
      (__attribute__((address_space(3))) void*)lds, 16, 0, 0);
}

// ---------------------------------------------------------------------------
// Fused fp32 -> fp16 conversion of x, in_proj_w, out_proj_w (one launch).
// ---------------------------------------------------------------------------
__global__ __launch_bounds__(256)
void cvt3_f32_f16(const float* __restrict__ a, _Float16* __restrict__ oa, int na,
                  const float* __restrict__ b, _Float16* __restrict__ ob, int nb,
                  const float* __restrict__ c, _Float16* __restrict__ oc, int nc) {
  int i = (blockIdx.x * 256 + threadIdx.x) * 8;
  const float* src;
  _Float16* dst;
  if (i < na) {
    src = a + i; dst = oa + i;
  } else if (i < na + nb) {
    src = b + (i - na); dst = ob + (i - na);
  } else if (i < na + nb + nc) {
    src = c + (i - na - nb); dst = oc + (i - na - nb);
  } else {
    return;
  }
  float4 p = *(const float4*)src;
  float4 q = *(const float4*)(src + 4);
  half8 h = {(_Float16)p.x, (_Float16)p.y, (_Float16)p.z, (_Float16)p.w,
             (_Float16)q.x, (_Float16)q.y, (_Float16)q.z, (_Float16)q.w};
  *(half8*)dst = h;
}

// ---------------------------------------------------------------------------
// MFMA GEMM (NT) v2 (R7-verified): double-buffered LDS, ONE barrier per
// K-iter, async global_load_lds staging, fp16 in, fp32 acc. BK=64.
// ---------------------------------------------------------------------------
template <int TM, int TN, int WR, int WC, int EPI>
__global__ __launch_bounds__(256)
void gemm_mfma(const _Float16* __restrict__ A, const _Float16* __restrict__ B,
               const float* __restrict__ bias, float* __restrict__ C,
               _Float16* __restrict__ qk, _Float16* __restrict__ vt,
               int M, int N, int K) {
  constexpr int RT = TM / (16 * WR);
  constexpr int CT = TN / (16 * WC);
  constexpr int ACH = TM / 8;
  constexpr int NCH = (TM + TN) / 32;

  __shared__ _Float16 As[2][TM * 64];
  __shared__ _Float16 Bs[2][TN * 64];

  const int tid = threadIdx.x;
  const int wave = tid >> 6, lane = tid & 63;
  const int l15 = lane & 15, quad = lane >> 4;
  const int wr = wave / WC, wc = wave % WC;
  const int row0 = blockIdx.y * TM, col0 = blockIdx.x * TN;

  const int srow = lane >> 3;
  const int gc = (lane & 7) ^ srow;

  auto stage = [&](int buf, int k0) {
#pragma unroll
    for (int c = 0; c < NCH; ++c) {
      int chunk = wave * NCH + c;
      if (chunk < ACH) {
        int row = chunk * 8 + srow;
        gload16((const char*)(A + (size_t)(row0 + row) * K + k0) + gc * 16,
                (char*)&As[buf][0] + chunk * 1024);
      } else {
        int bch = chunk - ACH;
        int row = bch * 8 + srow;
        gload16((const char*)(B + (size_t)(col0 + row) * K + k0) + gc * 16,
                (char*)&Bs[buf][0] + bch * 1024);
      }
    }
  };

  floatx4 acc[RT][CT];
#pragma unroll
  for (int i = 0; i < RT; ++i)
#pragma unroll
    for (int j = 0; j < CT; ++j) acc[i][j] = (floatx4){0.f, 0.f, 0.f, 0.f};

  const int niter = K / 64;
  stage(0, 0);

  for (int it = 0; it < niter; ++it) {
    const int cur = it & 1;
    __syncthreads();  // buf[cur] loads landed during previous compute
    if (it + 1 < niter) stage(cur ^ 1, (it + 1) * 64);

#pragma unroll
    for (int ks = 0; ks < 2; ++ks) {
      half8 af[RT], bf[CT];
#pragma unroll
      for (int t = 0; t < RT; ++t) {
        int r = wr * (16 * RT) + t * 16 + l15;
        af[t] = *(const half8*)&As[cur][r * 64 + (((ks * 4 + quad) ^ (r & 7)) * 8)];
      }
#pragma unroll
      for (int t = 0; t < CT; ++t) {
        int r = wc * (16 * CT) + t * 16 + l15;
        bf[t] = *(const half8*)&Bs[cur][r * 64 + (((ks * 4 + quad) ^ (r & 7)) * 8)];
      }
#pragma unroll
      for (int tr = 0; tr < RT; ++tr)
#pragma unroll
        for (int tc = 0; tc < CT; ++tc)
          acc[tr][tc] = __builtin_amdgcn_mfma_f32_16x16x32_f16(
              af[tr], bf[tc], acc[tr][tc], 0, 0, 0);
    }
  }

  const int crow = row0 + wr * (16 * RT);
  const int ccol = col0 + wc * (16 * CT);

  if (EPI == 0) {
#pragma unroll
    for (int tc = 0; tc < CT; ++tc) {
      int col = ccol + tc * 16 + l15;
      float bb = bias[col];
#pragma unroll
      for (int tr = 0; tr < RT; ++tr)
#pragma unroll
        for (int r = 0; r < 4; ++r)
          C[(size_t)(crow + tr * 16 + quad * 4 + r) * N + col] =
              acc[tr][tc][r] + bb;
    }
  } else if (col0 < 2 * E_DIM) {
#pragma unroll
    for (int tc = 0; tc < CT; ++tc) {
      int col = ccol + tc * 16 + l15;
      float bb = bias[col];
#pragma unroll
      for (int tr = 0; tr < RT; ++tr)
#pragma unroll
        for (int r = 0; r < 4; ++r)
          qk[(size_t)(crow + tr * 16 + quad * 4 + r) * (2 * E_DIM) + col] =
              (_Float16)(acc[tr][tc][r] + bb);
    }
  } else {
#pragma unroll
    for (int tc = 0; tc < CT; ++tc) {
      int col = ccol + tc * 16 + l15;
      float bb = bias[col];
      int vrow = col - 2 * E_DIM;
#pragma unroll
      for (int tr = 0; tr < RT; ++tr) {
        int rbase = crow + tr * 16 + quad * 4;
        half4 h = {(_Float16)(acc[tr][tc][0] + bb), (_Float16)(acc[tr][tc][1] + bb),
                   (_Float16)(acc[tr][tc][2] + bb), (_Float16)(acc[tr][tc][3] + bb)};
        *(half4*)&vt[(size_t)vrow * L_SEQ + rbase] = h;
      }
    }
  }
}

// ---------------------------------------------------------------------------
// MFMA flash attention v10 = v5 (proven 70us) + GEMM-style XOR bank swizzle.
// Schedule byte-identical to v5: grid (H, L/128)=256 blocks, 512 thr=8 waves,
// wave owns 16 q-rows, Bc=64 keys/iter, 32 iters, double-buffered K/V LDS,
// one barrier/iter, reg-prefetch of next tile + bias, S^T=K*Q^T, no-max
// softmax, Ps round-trip, x32 PV (v9's x16 PV regressed).
// v10 ONLY change: LDS layouts lose their pad (Ks [64][128], Vst [128][64],
// Ps [128][64] — power-of-2 rows == 0 mod bank-cycle) and every access
// XOR-swizzles its 16B-chunk index with (row&7). v5's padded rows folded each
// 16-lane phase into 128B of bank space (2x LDS-pipe serialization, 9.96M
// conflict cycles ~= 16us/CU); this is the exact geometry the GEMM's As/Bs
// use, which measures ZERO conflicts.
// ---------------------------------------------------------------------------
__global__ __launch_bounds__(512, 2)
void attn_mfma(const _Float16* __restrict__ qk, const _Float16* __restrict__ vt,
               const float* __restrict__ bias, _Float16* __restrict__ ctx) {
  const int h = blockIdx.x;
  const int q0 = blockIdx.y * 128;
  const int tid = threadIdx.x;
  const int wave = tid >> 6;
  const int lane = tid & 63;
  const int l15 = lane & 15;
  const int quad = lane >> 4;

  __shared__ _Float16 Ks[2][64][128];   // [buf][key][d], chunk^=(key&7)
  __shared__ _Float16 Vst[2][128][64];  // [buf][d][key], chunk^=(d&7)
  __shared__ _Float16 Ps[128][64];      // [q][key],      chunk^=(q&7)

  // Q fragments (B-operand: B[k=quad*8+j][n=l15=q]):
  half8 qa[4];
  {
    const _Float16* qp = qk + (size_t)(q0 + wave * 16 + l15) * (2 * E_DIM) +
                         h * D_HEAD + quad * 8;
#pragma unroll
    for (int ks = 0; ks < 4; ++ks) qa[ks] = *(const half8*)(qp + ks * 32);
  }

  float l_i = 0.f;
  floatx4 o[8];
#pragma unroll
  for (int t = 0; t < 8; ++t) o[t] = (floatx4){0.f, 0.f, 0.f, 0.f};

  const float scale = 0.088388347648318447f;  // 1/sqrt(128)

  // staging (512 threads, 2 chunks each of K and V):
  half8 kreg[2], vreg[2];
  floatx4 bcur[4], bnxt[4];
#pragma unroll
  for (int c = 0; c < 2; ++c) {
    int m = c * 512 + tid;
    kreg[c] = *(const half8*)(qk + (size_t)(m >> 4) * (2 * E_DIM) + E_DIM +
                              h * D_HEAD + (m & 15) * 8);
    vreg[c] = *(const half8*)(vt + (size_t)(h * D_HEAD + (m >> 3)) * L_SEQ +
                              (m & 7) * 8);
  }
#pragma unroll
  for (int t = 0; t < 4; ++t)
    bcur[t] = *(const floatx4*)&bias[(size_t)(q0 + wave * 16 + l15) * L_SEQ +
                                    16 * t + quad * 4];
#pragma unroll
  for (int c = 0; c < 2; ++c) {
    int m = c * 512 + tid;
    *(half8*)&Ks[0][m >> 4][(((m & 15) ^ ((m >> 4) & 7)) * 8)] = kreg[c];
    *(half8*)&Vst[0][m >> 3][(((m & 7) ^ ((m >> 3) & 7)) * 8)] = vreg[c];
  }

#pragma unroll 2
  for (int it = 0; it < 32; ++it) {
    const int cur = it & 1, nxt = cur ^ 1;
    const int kt = it * 64;
    __syncthreads();  // buf[cur] writes visible; buf[nxt] readers (it-1) done

    if (it < 31) {
#pragma unroll
      for (int c = 0; c < 2; ++c) {
        int m = c * 512 + tid;
        kreg[c] = *(const half8*)(qk + (size_t)(kt + 64 + (m >> 4)) * (2 * E_DIM) +
                                  E_DIM + h * D_HEAD + (m & 15) * 8);
        vreg[c] = *(const half8*)(vt + (size_t)(h * D_HEAD + (m >> 3)) * L_SEQ +
                                  kt + 64 + (m & 7) * 8);
      }
#pragma unroll
      for (int t = 0; t < 4; ++t)
        bnxt[t] = *(const floatx4*)&bias[(size_t)(q0 + wave * 16 + l15) * L_SEQ +
                                         kt + 64 + 16 * t + quad * 4];
    }

    // ---- S^T = K Q^T : col=l15=q, row=quad*4+reg=key(within 16t) ----
    floatx4 st[4];
#pragma unroll
    for (int t = 0; t < 4; ++t) st[t] = (floatx4){0.f, 0.f, 0.f, 0.f};
#pragma unroll
    for (int ks = 0; ks < 4; ++ks)
#pragma unroll
      for (int t = 0; t < 4; ++t) {
        half8 kf = *(const half8*)&Ks[cur][16 * t + l15]
                                      [(((ks * 4 + quad) ^ (l15 & 7)) * 8)];
        st[t] = __builtin_amdgcn_mfma_f32_16x16x32_f16(kf, qa[ks], st[t], 0, 0, 0);
      }

    // ---- softmax (no max subtraction) + P^T pack -> Ps[q][key] ----
    {
      float ls = 0.f;
      float ps[4][4];
#pragma unroll
      for (int t = 0; t < 4; ++t)
#pragma unroll
        for (int r = 0; r < 4; ++r) {
          float p = __expf(fmaf(st[t][r], scale, bcur[t][r]));
          ps[t][r] = p;
          ls += p;
        }
      ls += __shfl_xor(ls, 16);
      ls += __shfl_xor(ls, 32);
      l_i += ls;
#pragma unroll
      for (int t = 0; t < 4; ++t) {
        half4 hp = {(_Float16)ps[t][0], (_Float16)ps[t][1],
                    (_Float16)ps[t][2], (_Float16)ps[t][3]};
        // 16B chunk = 2t + (quad>>1), 8B sub = quad&1, chunk ^= (q-row & 7)
        *(half4*)&Ps[wave * 16 + l15]
                    [((((2 * t + (quad >> 1)) ^ (l15 & 7)) * 8) + (quad & 1) * 4)] =
            hp;
      }
    }

    // ---- O += P V (A=P own rows; B=V^T; same-wave, no barrier) ----
    half8 pa[2];
#pragma unroll
    for (int ks = 0; ks < 2; ++ks)
      pa[ks] = *(const half8*)&Ps[wave * 16 + l15]
                                 [(((ks * 4 + quad) ^ (l15 & 7)) * 8)];
#pragma unroll
    for (int t = 0; t < 8; ++t)
#pragma unroll
      for (int ks = 0; ks < 2; ++ks) {
        half8 vf = *(const half8*)&Vst[cur][16 * t + l15]
                                       [(((ks * 4 + quad) ^ (l15 & 7)) * 8)];
        o[t] = __builtin_amdgcn_mfma_f32_16x16x32_f16(pa[ks], vf, o[t], 0, 0, 0);
      }

    if (it < 31) {
#pragma unroll
      for (int c = 0; c < 2; ++c) {
        int m = c * 512 + tid;
        *(half8*)&Ks[nxt][m >> 4][(((m & 15) ^ ((m >> 4) & 7)) * 8)] = kreg[c];
        *(half8*)&Vst[nxt][m >> 3][(((m & 7) ^ ((m >> 3) & 7)) * 8)] = vreg[c];
      }
#pragma unroll
      for (int t = 0; t < 4; ++t) bcur[t] = bnxt[t];
    }
  }

  // ---- epilogue: ctx = O / l. l lives at lane l15=q; o rows are quad*4+r ----
  float inv[4];
#pragma unroll
  for (int r = 0; r < 4; ++r) inv[r] = 1.f / __shfl(l_i, quad * 4 + r);
#pragma unroll
  for (int t = 0; t < 8; ++t)
#pragma unroll
    for (int r = 0; r < 4; ++r) {
      int row = q0 + wave * 16 + quad * 4 + r;
      ctx[(size_t)row * E_DIM + h * D_HEAD + 16 * t + l15] =
          (_Float16)(o[t][r] * inv[r]);
    }
}

// ---------------------------------------------------------------------------
extern "C" void kernel_launch(void* const* d_in, const int* in_sizes, int n_in,
                              void* d_out, int out_size, void* d_ws, size_t ws_size,
                              hipStream_t stream) {
  const float* x          = (const float*)d_in[0];
  const float* bias_mat   = (const float*)d_in[1];
  const float* in_proj_w  = (const float*)d_in[2];
  const float* in_proj_b  = (const float*)d_in[3];
  const float* out_proj_w = (const float*)d_in[4];
  const float* out_proj_b = (const float*)d_in[5];
  float* out = (float*)d_out;

  _Float16* x16 = (_Float16*)d_ws;                         // L*E
  _Float16* w1  = x16 + (size_t)L_SEQ * E_DIM;             // 3E*E
  _Float16* w2  = w1 + (size_t)3 * E_DIM * E_DIM;          // E*E
  _Float16* qk  = w2 + (size_t)E_DIM * E_DIM;              // L*2E
  _Float16* vt  = qk + (size_t)L_SEQ * 2 * E_DIM;          // E*L
  _Float16* ctx = vt + (size_t)E_DIM * L_SEQ;              // L*E

  dim3 blk(256);
  const int nx = L_SEQ * E_DIM, nw1 = 3 * E_DIM * E_DIM, nw2 = E_DIM * E_DIM;

  cvt3_f32_f16<<<(nx + nw1 + nw2) / 2048, blk, 0, stream>>>(
      x, x16, nx, in_proj_w, w1, nw1, out_proj_w, w2, nw2);

  gemm_mfma<128, 128, 2, 2, 1><<<dim3(3 * E_DIM / 128, L_SEQ / 128), blk, 0, stream>>>(
      x16, w1, in_proj_b, nullptr, qk, vt, L_SEQ, 3 * E_DIM, E_DIM);

  attn_mfma<<<dim3(H_NUM, L_SEQ / 128), dim3(512), 0, stream>>>(qk, vt, bias_mat,
                                                                ctx);

  gemm_mfma<128, 64, 4, 1, 0><<<dim3(E_DIM / 64, L_SEQ / 128), blk, 0, stream>>>(
      ctx, w2, out_proj_b, out, nullptr, nullptr, L_SEQ, E_DIM, E_DIM);
}

// Round 7
// 281.242 us; speedup vs baseline: 1.4203x; 1.0118x over previous
//
#include <hip/hip_runtime.h>
#include <math.h>

#define L_SEQ 2048
#define E_DIM 2048
#define H_NUM 16
#define D_HEAD 128

typedef __attribute__((ext_vector_type(8))) _Float16 half8;
typedef __attribute__((ext_vector_type(4))) _Float16 half4;
typedef __attribute__((ext_vector_type(4))) float floatx4;

// async global->LDS, 16B per lane. LDS dest is wave-uniform base + lane*16.
static __device__ __forceinline__ void gload16(const void* g, void* lds) {
  __builtin_amdgcn_global_load_lds(
      (const __attribute__((address_space(1))) void*)g,
      (__attribute__((address_space(3))) void*)lds, 16, 0, 0);
}

// ---------------------------------------------------------------------------
// Fused fp32 -> fp16 conversion of x, in_proj_w, out_proj_w (one launch).
// ---------------------------------------------------------------------------
__global__ __launch_bounds__(256)
void cvt3_f32_f16(const float* __restrict__ a, _Float16* __restrict__ oa, int na,
                  const float* __restrict__ b, _Float16* __restrict__ ob, int nb,
                  const float* __restrict__ c, _Float16* __restrict__ oc, int nc) {
  int i = (blockIdx.x * 256 + threadIdx.x) * 8;
  const float* src;
  _Float16* dst;
  if (i < na) {
    src = a + i; dst = oa + i;
  } else if (i < na + nb) {
    src = b + (i - na); dst = ob + (i - na);
  } else if (i < na + nb + nc) {
    src = c + (i - na - nb); dst = oc + (i - na - nb);
  } else {
    return;
  }
  float4 p = *(const float4*)src;
  float4 q = *(const float4*)(src + 4);
  half8 h = {(_Float16)p.x, (_Float16)p.y, (_Float16)p.z, (_Float16)p.w,
             (_Float16)q.x, (_Float16)q.y, (_Float16)q.z, (_Float16)q.w};
  *(half8*)dst = h;
}

// ---------------------------------------------------------------------------
// QKV GEMM v3: 256x256 tile, BK=64, 512 thr = 8 waves (2M x 4N), counted-vmcnt
// granule pipeline (T3+T4). LDS 128KB = {A,B} x 2dbuf x 2(k-half) granules of
// 16KB ([256 rows][32 halfs], 16B-chunk swizzle c^(row&3), staged via
// global_load_lds with pre-swizzled global source, linear LDS dest).
// Ring schedule (tile T, phases A=ks0 / B=ks1):
//   phA: vmcnt(8) [Akh0(T),Bkh0(T) landed; 8 newer fly]; barrier;
//        stage Akh1(T+1),Bkh1(T+1); compute ks0 (12 ds_read_b128, 32 MFMA)
//   phB: vmcnt(8) [Akh1(T),Bkh1(T) landed]; barrier;
//        stage Akh0(T+2),Bkh0(T+2); compute ks1
// Every granule staged >=5 phases before use (~775cyc compute cover ~= HBM
// latency); every stage-issue is barrier-ordered after its slot's last
// reader; vmcnt never drains to 0 until the peeled final tile.
// lgkmcnt(0) folded into each wait: raw s_barrier implies no waits, and the
// extra wait is free (ds_reads already drained by MFMA operand waits).
// ---------------------------------------------------------------------------
__global__ __launch_bounds__(512, 1)
void gemm_qkv(const _Float16* __restrict__ A, const _Float16* __restrict__ B,
              const float* __restrict__ bias, _Float16* __restrict__ qk,
              _Float16* __restrict__ vt) {
  constexpr int K = E_DIM;  // 2048, 32 K-tiles of 64
  __shared__ __align__(16) char smem[131072];
  char* const Asm = smem;            // [dbuf2][kh2] granules of 16KB
  char* const Bsm = smem + 65536;

  const int tid = threadIdx.x;
  const int wave = tid >> 6, lane = tid & 63;
  const int l15 = lane & 15, quad = lane >> 4;
  const int wm = wave >> 2, wn = wave & 3;
  const int brow = blockIdx.y * 256, bcol = blockIdx.x * 256;

  const _Float16* Ag = A + (size_t)brow * K;
  const _Float16* Bg = B + (size_t)bcol * K;

  // stage granule kh of K-tile T (16KB = 2 gload16/thread), FIFO-ordered.
  auto stg = [&](char* smbase, const _Float16* gbase, int T, int kh) {
    char* slot = smbase + ((T & 1) * 2 + kh) * 16384;
#pragma unroll
    for (int j = 0; j < 2; ++j) {
      int mb = j * 512 + (tid & ~63);  // wave-uniform chunk base
      int m = mb + (tid & 63);
      int row = m >> 2, c = m & 3;
      gload16(gbase + (size_t)row * K + T * 64 + kh * 32 + ((c ^ (row & 3)) * 8),
              slot + mb * 16);
    }
  };

  floatx4 acc[8][4];
#pragma unroll
  for (int i = 0; i < 8; ++i)
#pragma unroll
    for (int j = 0; j < 4; ++j) acc[i][j] = (floatx4){0.f, 0.f, 0.f, 0.f};

  auto compute_phase = [&](int T, int ks) {
    const char* Ab = Asm + ((T & 1) * 2 + ks) * 16384;
    const char* Bb = Bsm + ((T & 1) * 2 + ks) * 16384;
    half8 af[8], bf[4];
#pragma unroll
    for (int t = 0; t < 8; ++t)
      af[t] = *(const half8*)(Ab + (size_t)(wm * 128 + t * 16 + l15) * 64 +
                              ((quad ^ (l15 & 3)) * 16));
#pragma unroll
    for (int t = 0; t < 4; ++t)
      bf[t] = *(const half8*)(Bb + (size_t)(wn * 64 + t * 16 + l15) * 64 +
                              ((quad ^ (l15 & 3)) * 16));
#pragma unroll
    for (int i = 0; i < 8; ++i)
#pragma unroll
      for (int j = 0; j < 4; ++j)
        acc[i][j] = __builtin_amdgcn_mfma_f32_16x16x32_f16(af[i], bf[j],
                                                           acc[i][j], 0, 0, 0);
  };

  // prologue: FIFO = Akh0(0),Bkh0(0),Akh1(0),Bkh1(0),Akh0(1),Bkh0(1)
  stg(Asm, Ag, 0, 0); stg(Bsm, Bg, 0, 0);
  stg(Asm, Ag, 0, 1); stg(Bsm, Bg, 0, 1);
  stg(Asm, Ag, 1, 0); stg(Bsm, Bg, 1, 0);

  for (int T = 0; T < 31; ++T) {
    // ---- phase A (ks=0) ----
    __builtin_amdgcn_sched_barrier(0);
    asm volatile("s_waitcnt vmcnt(8) lgkmcnt(0)" ::: "memory");
    __builtin_amdgcn_s_barrier();
    __builtin_amdgcn_sched_barrier(0);
    stg(Asm, Ag, T + 1, 1);
    stg(Bsm, Bg, T + 1, 1);
    compute_phase(T, 0);
    // ---- phase B (ks=1) ----
    __builtin_amdgcn_sched_barrier(0);
    asm volatile("s_waitcnt vmcnt(8) lgkmcnt(0)" ::: "memory");
    __builtin_amdgcn_s_barrier();
    __builtin_amdgcn_sched_barrier(0);
    if (T < 30) {
      stg(Asm, Ag, T + 2, 0);
      stg(Bsm, Bg, T + 2, 0);
    }
    compute_phase(T, 1);
  }
  // ---- T = 31 peeled (drain) ----
  __builtin_amdgcn_sched_barrier(0);
  asm volatile("s_waitcnt vmcnt(4) lgkmcnt(0)" ::: "memory");
  __builtin_amdgcn_s_barrier();
  __builtin_amdgcn_sched_barrier(0);
  compute_phase(31, 0);
  __builtin_amdgcn_sched_barrier(0);
  asm volatile("s_waitcnt vmcnt(0) lgkmcnt(0)" ::: "memory");
  __builtin_amdgcn_s_barrier();
  __builtin_amdgcn_sched_barrier(0);
  compute_phase(31, 1);

  // ---- epilogue: qk fp16 (cols < 2E) or vt transposed fp16 ----
  const int crow = brow + wm * 128;
  const int ccol0 = bcol + wn * 64;
  if (bcol < 2 * E_DIM) {
#pragma unroll
    for (int j = 0; j < 4; ++j) {
      int col = ccol0 + j * 16 + l15;
      float bb = bias[col];
#pragma unroll
      for (int i = 0; i < 8; ++i)
#pragma unroll
        for (int r = 0; r < 4; ++r)
          qk[(size_t)(crow + i * 16 + quad * 4 + r) * (2 * E_DIM) + col] =
              (_Float16)(acc[i][j][r] + bb);
    }
  } else {
#pragma unroll
    for (int j = 0; j < 4; ++j) {
      int col = ccol0 + j * 16 + l15;
      float bb = bias[col];
      int vrow = col - 2 * E_DIM;
#pragma unroll
      for (int i = 0; i < 8; ++i) {
        int rbase = crow + i * 16 + quad * 4;
        half4 h = {(_Float16)(acc[i][j][0] + bb), (_Float16)(acc[i][j][1] + bb),
                   (_Float16)(acc[i][j][2] + bb), (_Float16)(acc[i][j][3] + bb)};
        *(half4*)&vt[(size_t)vrow * L_SEQ + rbase] = h;
      }
    }
  }
}

// ---------------------------------------------------------------------------
// MFMA GEMM (NT) v2 (R7-verified): out-proj only.
// ---------------------------------------------------------------------------
template <int TM, int TN, int WR, int WC>
__global__ __launch_bounds__(256)
void gemm_mfma(const _Float16* __restrict__ A, const _Float16* __restrict__ B,
               const float* __restrict__ bias, float* __restrict__ C,
               int M, int N, int K) {
  constexpr int RT = TM / (16 * WR);
  constexpr int CT = TN / (16 * WC);
  constexpr int ACH = TM / 8;
  constexpr int NCH = (TM + TN) / 32;

  __shared__ _Float16 As[2][TM * 64];
  __shared__ _Float16 Bs[2][TN * 64];

  const int tid = threadIdx.x;
  const int wave = tid >> 6, lane = tid & 63;
  const int l15 = lane & 15, quad = lane >> 4;
  const int wr = wave / WC, wc = wave % WC;
  const int row0 = blockIdx.y * TM, col0 = blockIdx.x * TN;

  const int srow = lane >> 3;
  const int gc = (lane & 7) ^ srow;

  auto stage = [&](int buf, int k0) {
#pragma unroll
    for (int c = 0; c < NCH; ++c) {
      int chunk = wave * NCH + c;
      if (chunk < ACH) {
        int row = chunk * 8 + srow;
        gload16((const char*)(A + (size_t)(row0 + row) * K + k0) + gc * 16,
                (char*)&As[buf][0] + chunk * 1024);
      } else {
        int bch = chunk - ACH;
        int row = bch * 8 + srow;
        gload16((const char*)(B + (size_t)(col0 + row) * K + k0) + gc * 16,
                (char*)&Bs[buf][0] + bch * 1024);
      }
    }
  };

  floatx4 acc[RT][CT];
#pragma unroll
  for (int i = 0; i < RT; ++i)
#pragma unroll
    for (int j = 0; j < CT; ++j) acc[i][j] = (floatx4){0.f, 0.f, 0.f, 0.f};

  const int niter = K / 64;
  stage(0, 0);

  for (int it = 0; it < niter; ++it) {
    const int cur = it & 1;
    __syncthreads();
    if (it + 1 < niter) stage(cur ^ 1, (it + 1) * 64);

#pragma unroll
    for (int ks = 0; ks < 2; ++ks) {
      half8 af[RT], bf[CT];
#pragma unroll
      for (int t = 0; t < RT; ++t) {
        int r = wr * (16 * RT) + t * 16 + l15;
        af[t] = *(const half8*)&As[cur][r * 64 + (((ks * 4 + quad) ^ (r & 7)) * 8)];
      }
#pragma unroll
      for (int t = 0; t < CT; ++t) {
        int r = wc * (16 * CT) + t * 16 + l15;
        bf[t] = *(const half8*)&Bs[cur][r * 64 + (((ks * 4 + quad) ^ (r & 7)) * 8)];
      }
#pragma unroll
      for (int tr = 0; tr < RT; ++tr)
#pragma unroll
        for (int tc = 0; tc < CT; ++tc)
          acc[tr][tc] = __builtin_amdgcn_mfma_f32_16x16x32_f16(
              af[tr], bf[tc], acc[tr][tc], 0, 0, 0);
    }
  }

  const int crow = row0 + wr * (16 * RT);
  const int ccol = col0 + wc * (16 * CT);

#pragma unroll
  for (int tc = 0; tc < CT; ++tc) {
    int col = ccol + tc * 16 + l15;
    float bb = bias[col];
#pragma unroll
    for (int tr = 0; tr < RT; ++tr)
#pragma unroll
      for (int r = 0; r < 4; ++r)
        C[(size_t)(crow + tr * 16 + quad * 4 + r) * N + col] =
            acc[tr][tc][r] + bb;
  }
}

// ---------------------------------------------------------------------------
// MFMA flash attention v5 (proven 70us local optimum — rounds 1-5 all lost).
// Grid (H, L/128) = 256 blocks, 512 thr = 8 waves. Wave owns 16 q-rows.
// Bc=64 keys/iter, 32 iters, double-buffered K/V LDS, one barrier/iter,
// reg-prefetch of next tile + bias, S^T=K*Q^T trick, no-max softmax.
// ---------------------------------------------------------------------------
__global__ __launch_bounds__(512, 2)
void attn_mfma(const _Float16* __restrict__ qk, const _Float16* __restrict__ vt,
               const float* __restrict__ bias, _Float16* __restrict__ ctx) {
  const int h = blockIdx.x;
  const int q0 = blockIdx.y * 128;
  const int tid = threadIdx.x;
  const int wave = tid >> 6;
  const int lane = tid & 63;
  const int l15 = lane & 15;
  const int quad = lane >> 4;

  __shared__ _Float16 Ks[2][64][136];   // [buf][key][d]
  __shared__ _Float16 Vst[2][128][72];  // [buf][d][key]
  __shared__ _Float16 Ps[128][72];      // [q][key] (same-wave use only)

  // Q fragments (B-operand: B[k=quad*8+j][n=l15=q]):
  half8 qa[4];
  {
    const _Float16* qp = qk + (size_t)(q0 + wave * 16 + l15) * (2 * E_DIM) +
                         h * D_HEAD + quad * 8;
#pragma unroll
    for (int ks = 0; ks < 4; ++ks) qa[ks] = *(const half8*)(qp + ks * 32);
  }

  float l_i = 0.f;
  floatx4 o[8];
#pragma unroll
  for (int t = 0; t < 8; ++t) o[t] = (floatx4){0.f, 0.f, 0.f, 0.f};

  const float scale = 0.088388347648318447f;  // 1/sqrt(128)

  // staging (512 threads, 2 chunks each of K and V):
  half8 kreg[2], vreg[2];
  floatx4 bcur[4], bnxt[4];
#pragma unroll
  for (int c = 0; c < 2; ++c) {
    int m = c * 512 + tid;
    kreg[c] = *(const half8*)(qk + (size_t)(m >> 4) * (2 * E_DIM) + E_DIM +
                              h * D_HEAD + (m & 15) * 8);
    vreg[c] = *(const half8*)(vt + (size_t)(h * D_HEAD + (m >> 3)) * L_SEQ +
                              (m & 7) * 8);
  }
#pragma unroll
  for (int t = 0; t < 4; ++t)
    bcur[t] = *(const floatx4*)&bias[(size_t)(q0 + wave * 16 + l15) * L_SEQ +
                                    16 * t + quad * 4];
#pragma unroll
  for (int c = 0; c < 2; ++c) {
    int m = c * 512 + tid;
    *(half8*)&Ks[0][m >> 4][(m & 15) * 8] = kreg[c];
    *(half8*)&Vst[0][m >> 3][(m & 7) * 8] = vreg[c];
  }

#pragma unroll 2
  for (int it = 0; it < 32; ++it) {
    const int cur = it & 1, nxt = cur ^ 1;
    const int kt = it * 64;
    __syncthreads();  // buf[cur] writes visible; buf[nxt] readers (it-1) done

    if (it < 31) {
#pragma unroll
      for (int c = 0; c < 2; ++c) {
        int m = c * 512 + tid;
        kreg[c] = *(const half8*)(qk + (size_t)(kt + 64 + (m >> 4)) * (2 * E_DIM) +
                                  E_DIM + h * D_HEAD + (m & 15) * 8);
        vreg[c] = *(const half8*)(vt + (size_t)(h * D_HEAD + (m >> 3)) * L_SEQ +
                                  kt + 64 + (m & 7) * 8);
      }
#pragma unroll
      for (int t = 0; t < 4; ++t)
        bnxt[t] = *(const floatx4*)&bias[(size_t)(q0 + wave * 16 + l15) * L_SEQ +
                                         kt + 64 + 16 * t + quad * 4];
    }

    // ---- S^T = K Q^T : col=l15=q, row=quad*4+reg=key(within 16t) ----
    floatx4 st[4];
#pragma unroll
    for (int t = 0; t < 4; ++t) st[t] = (floatx4){0.f, 0.f, 0.f, 0.f};
#pragma unroll
    for (int ks = 0; ks < 4; ++ks)
#pragma unroll
      for (int t = 0; t < 4; ++t) {
        half8 kf = *(const half8*)&Ks[cur][16 * t + l15][ks * 32 + quad * 8];
        st[t] = __builtin_amdgcn_mfma_f32_16x16x32_f16(kf, qa[ks], st[t], 0, 0, 0);
      }

    // ---- softmax (no max subtraction) + P^T pack -> Ps[q][key] ----
    {
      float ls = 0.f;
      float ps[4][4];
#pragma unroll
      for (int t = 0; t < 4; ++t)
#pragma unroll
        for (int r = 0; r < 4; ++r) {
          float p = __expf(fmaf(st[t][r], scale, bcur[t][r]));
          ps[t][r] = p;
          ls += p;
        }
      ls += __shfl_xor(ls, 16);
      ls += __shfl_xor(ls, 32);
      l_i += ls;
#pragma unroll
      for (int t = 0; t < 4; ++t) {
        half4 hp = {(_Float16)ps[t][0], (_Float16)ps[t][1],
                    (_Float16)ps[t][2], (_Float16)ps[t][3]};
        *(half4*)&Ps[wave * 16 + l15][16 * t + quad * 4] = hp;
      }
    }

    // ---- O += P V (A=P own rows; B=V^T; same-wave, no barrier) ----
    half8 pa[2];
#pragma unroll
    for (int ks = 0; ks < 2; ++ks)
      pa[ks] = *(const half8*)&Ps[wave * 16 + l15][ks * 32 + quad * 8];
#pragma unroll
    for (int t = 0; t < 8; ++t)
#pragma unroll
      for (int ks = 0; ks < 2; ++ks) {
        half8 vf = *(const half8*)&Vst[cur][16 * t + l15][ks * 32 + quad * 8];
        o[t] = __builtin_amdgcn_mfma_f32_16x16x32_f16(pa[ks], vf, o[t], 0, 0, 0);
      }

    if (it < 31) {
#pragma unroll
      for (int c = 0; c < 2; ++c) {
        int m = c * 512 + tid;
        *(half8*)&Ks[nxt][m >> 4][(m & 15) * 8] = kreg[c];
        *(half8*)&Vst[nxt][m >> 3][(m & 7) * 8] = vreg[c];
      }
#pragma unroll
      for (int t = 0; t < 4; ++t) bcur[t] = bnxt[t];
    }
  }

  // ---- epilogue: ctx = O / l. l lives at lane l15=q; o rows are quad*4+r ----
  float inv[4];
#pragma unroll
  for (int r = 0; r < 4; ++r) inv[r] = 1.f / __shfl(l_i, quad * 4 + r);
#pragma unroll
  for (int t = 0; t < 8; ++t)
#pragma unroll
    for (int r = 0; r < 4; ++r) {
      int row = q0 + wave * 16 + quad * 4 + r;
      ctx[(size_t)row * E_DIM + h * D_HEAD + 16 * t + l15] =
          (_Float16)(o[t][r] * inv[r]);
    }
}

// ---------------------------------------------------------------------------
extern "C" void kernel_launch(void* const* d_in, const int* in_sizes, int n_in,
                              void* d_out, int out_size, void* d_ws, size_t ws_size,
                              hipStream_t stream) {
  const float* x          = (const float*)d_in[0];
  const float* bias_mat   = (const float*)d_in[1];
  const float* in_proj_w  = (const float*)d_in[2];
  const float* in_proj_b  = (const float*)d_in[3];
  const float* out_proj_w = (const float*)d_in[4];
  const float* out_proj_b = (const float*)d_in[5];
  float* out = (float*)d_out;

  _Float16* x16 = (_Float16*)d_ws;                         // L*E
  _Float16* w1  = x16 + (size_t)L_SEQ * E_DIM;             // 3E*E
  _Float16* w2  = w1 + (size_t)3 * E_DIM * E_DIM;          // E*E
  _Float16* qk  = w2 + (size_t)E_DIM * E_DIM;              // L*2E
  _Float16* vt  = qk + (size_t)L_SEQ * 2 * E_DIM;          // E*L
  _Float16* ctx = vt + (size_t)E_DIM * L_SEQ;              // L*E

  dim3 blk(256);
  const int nx = L_SEQ * E_DIM, nw1 = 3 * E_DIM * E_DIM, nw2 = E_DIM * E_DIM;

  cvt3_f32_f16<<<(nx + nw1 + nw2) / 2048, blk, 0, stream>>>(
      x, x16, nx, in_proj_w, w1, nw1, out_proj_w, w2, nw2);

  gemm_qkv<<<dim3(3 * E_DIM / 256, L_SEQ / 256), dim3(512), 0, stream>>>(
      x16, w1, in_proj_b, qk, vt);

  attn_mfma<<<dim3(H_NUM, L_SEQ / 128), dim3(512), 0, stream>>>(qk, vt, bias_mat,
                                                                ctx);

  gemm_mfma<128, 64, 4, 1><<<dim3(E_DIM / 64, L_SEQ / 128), blk, 0, stream>>>(
      ctx, w2, out_proj_b, out, L_SEQ, E_DIM, E_DIM);
}

// Round 8
// 272.762 us; speedup vs baseline: 1.4645x; 1.0311x over previous
//
#include <hip/hip_runtime.h>
#include <math.h>

#define L_SEQ 2048
#define E_DIM 2048
#define H_NUM 16
#define D_HEAD 128

typedef __attribute__((ext_vector_type(8))) _Float16 half8;
typedef __attribute__((ext_vector_type(4))) _Float16 half4;
typedef __attribute__((ext_vector_type(4))) float floatx4;

// async global->LDS, 16B per lane. LDS dest is wave-uniform base + lane*16.
static __device__ __forceinline__ void gload16(const void* g, void* lds) {
  __builtin_amdgcn_global_load_lds(
      (const __attribute__((address_space(1))) void*)g,
      (__attribute__((address_space(3))) void*)lds, 16, 0, 0);
}

// ---------------------------------------------------------------------------
// Fused fp32 -> fp16 conversion of x, in_proj_w, out_proj_w (one launch).
// ---------------------------------------------------------------------------
__global__ __launch_bounds__(256)
void cvt3_f32_f16(const float* __restrict__ a, _Float16* __restrict__ oa, int na,
                  const float* __restrict__ b, _Float16* __restrict__ ob, int nb,
                  const float* __restrict__ c, _Float16* __restrict__ oc, int nc) {
  int i = (blockIdx.x * 256 + threadIdx.x) * 8;
  const float* src;
  _Float16* dst;
  if (i < na) {
    src = a + i; dst = oa + i;
  } else if (i < na + nb) {
    src = b + (i - na); dst = ob + (i - na);
  } else if (i < na + nb + nc) {
    src = c + (i - na - nb); dst = oc + (i - na - nb);
  } else {
    return;
  }
  float4 p = *(const float4*)src;
  float4 q = *(const float4*)(src + 4);
  half8 h = {(_Float16)p.x, (_Float16)p.y, (_Float16)p.z, (_Float16)p.w,
             (_Float16)q.x, (_Float16)q.y, (_Float16)q.z, (_Float16)q.w};
  *(half8*)dst = h;
}

// ---------------------------------------------------------------------------
// QKV GEMM v4: 128x384 tile -> grid (16,16) = 256 blocks (R7's 192-block
// 256sq left 25% of CUs idle). BK=64, 512 thr = 8 waves (2M x 4N), counted-
// vmcnt granule pipeline (verified R7). LDS 128KB = 4 slots x (A 8KB + B
// 24KB); granule rows 32 halfs, 16B-chunk swizzle c ^ ((row>>1)&3) — R7's
// c^(row&3) collided with the bank parity bit (4.7M conflict cycles, ~13%);
// the >>1 form covers all four 4-bank groups per parity (2/bank, minimal).
// Ring schedule per K-tile T (phases ks=0/1), 4 loads/thread/phase uniform:
//   phX: vmcnt(8)+lgkmcnt(0) [granule (T,ks) landed, 8 newer fly]; barrier;
//        stage granule 3 phases ahead; 10 ds_read_b128 + 24 MFMA.
// XCD swizzle: lid=(by*16+bx); swz=(lid&7)*32+lid/8 (bijective, 256%8==0) —
// each XCD's 32 blocks share 2 A-panels (1MB) in its private L2.
// ---------------------------------------------------------------------------
__global__ __launch_bounds__(512, 1)
void gemm_qkv(const _Float16* __restrict__ A, const _Float16* __restrict__ B,
              const float* __restrict__ bias, _Float16* __restrict__ qk,
              _Float16* __restrict__ vt) {
  constexpr int K = E_DIM;  // 2048, 32 K-tiles of 64
  __shared__ __align__(16) char smem[131072];
  char* const Asm = smem;            // 4 slots x 8KB  ([128 r][32 h])
  char* const Bsm = smem + 32768;    // 4 slots x 24KB ([384 r][32 h])

  const int tid = threadIdx.x;
  const int wave = tid >> 6, lane = tid & 63;
  const int l15 = lane & 15, quad = lane >> 4;
  const int wm = wave >> 2, wn = wave & 3;

  const int lid = blockIdx.y * 16 + blockIdx.x;
  const int swz = (lid & 7) * 32 + (lid >> 3);
  const int brow = (swz >> 4) * 128, bcol = (swz & 15) * 384;

  const _Float16* Ag = A + (size_t)brow * K;
  const _Float16* Bg = B + (size_t)bcol * K;

  // stage granule (T,kh): A 512 chunks (1 load/thr) + B 1536 chunks (3/thr).
  auto stg = [&](int T, int kh) {
    char* aslot = Asm + ((T & 1) * 2 + kh) * 8192;
    char* bslot = Bsm + ((T & 1) * 2 + kh) * 24576;
    {
      int row = tid >> 2, c = tid & 3;
      gload16(Ag + (size_t)row * K + T * 64 + kh * 32 +
                  ((c ^ ((row >> 1) & 3)) * 8),
              aslot + (tid & ~63) * 16);
    }
#pragma unroll
    for (int j = 0; j < 3; ++j) {
      int mb = j * 512 + (tid & ~63);
      int m = mb + (tid & 63);
      int row = m >> 2, c = m & 3;
      gload16(Bg + (size_t)row * K + T * 64 + kh * 32 +
                  ((c ^ ((row >> 1) & 3)) * 8),
              bslot + mb * 16);
    }
  };

  floatx4 acc[4][6];
#pragma unroll
  for (int i = 0; i < 4; ++i)
#pragma unroll
    for (int j = 0; j < 6; ++j) acc[i][j] = (floatx4){0.f, 0.f, 0.f, 0.f};

  auto compute_phase = [&](int T, int ks) {
    const char* Ab = Asm + ((T & 1) * 2 + ks) * 8192;
    const char* Bb = Bsm + ((T & 1) * 2 + ks) * 24576;
    half8 af[4], bf[6];
#pragma unroll
    for (int t = 0; t < 4; ++t) {
      int r = wm * 64 + t * 16 + l15;
      af[t] = *(const half8*)(Ab + (size_t)r * 64 +
                              ((quad ^ ((r >> 1) & 3)) * 16));
    }
#pragma unroll
    for (int t = 0; t < 6; ++t) {
      int r = wn * 96 + t * 16 + l15;
      bf[t] = *(const half8*)(Bb + (size_t)r * 64 +
                              ((quad ^ ((r >> 1) & 3)) * 16));
    }
#pragma unroll
    for (int i = 0; i < 4; ++i)
#pragma unroll
      for (int j = 0; j < 6; ++j)
        acc[i][j] = __builtin_amdgcn_mfma_f32_16x16x32_f16(af[i], bf[j],
                                                           acc[i][j], 0, 0, 0);
  };

  // prologue FIFO: (0,0),(0,1),(1,0) = 12 loads
  stg(0, 0); stg(0, 1); stg(1, 0);

  for (int T = 0; T < 31; ++T) {
    // ---- phase A (ks=0): consumes (T,0) ----
    __builtin_amdgcn_sched_barrier(0);
    asm volatile("s_waitcnt vmcnt(8) lgkmcnt(0)" ::: "memory");
    __builtin_amdgcn_s_barrier();
    __builtin_amdgcn_sched_barrier(0);
    stg(T + 1, 1);
    compute_phase(T, 0);
    // ---- phase B (ks=1): consumes (T,1) ----
    __builtin_amdgcn_sched_barrier(0);
    asm volatile("s_waitcnt vmcnt(8) lgkmcnt(0)" ::: "memory");
    __builtin_amdgcn_s_barrier();
    __builtin_amdgcn_sched_barrier(0);
    if (T < 30) stg(T + 2, 0);
    compute_phase(T, 1);
  }
  // ---- T = 31 peeled (drain: (31,0),(31,1) = 8 loads outstanding) ----
  __builtin_amdgcn_sched_barrier(0);
  asm volatile("s_waitcnt vmcnt(4) lgkmcnt(0)" ::: "memory");
  __builtin_amdgcn_s_barrier();
  __builtin_amdgcn_sched_barrier(0);
  compute_phase(31, 0);
  __builtin_amdgcn_sched_barrier(0);
  asm volatile("s_waitcnt vmcnt(0) lgkmcnt(0)" ::: "memory");
  __builtin_amdgcn_s_barrier();
  __builtin_amdgcn_sched_barrier(0);
  compute_phase(31, 1);

  // ---- epilogue: per 16-col fragment qk fp16 or vt transposed fp16 ----
  // (4096 % 16 == 0 -> each fragment is uniformly on one side)
  const int crow = brow + wm * 64;
  const int ccol0 = bcol + wn * 96;
#pragma unroll
  for (int j = 0; j < 6; ++j) {
    int col = ccol0 + j * 16 + l15;
    float bb = bias[col];
    if (col < 2 * E_DIM) {
#pragma unroll
      for (int i = 0; i < 4; ++i)
#pragma unroll
        for (int r = 0; r < 4; ++r)
          qk[(size_t)(crow + i * 16 + quad * 4 + r) * (2 * E_DIM) + col] =
              (_Float16)(acc[i][j][r] + bb);
    } else {
      int vrow = col - 2 * E_DIM;
#pragma unroll
      for (int i = 0; i < 4; ++i) {
        int rbase = crow + i * 16 + quad * 4;
        half4 h = {(_Float16)(acc[i][j][0] + bb), (_Float16)(acc[i][j][1] + bb),
                   (_Float16)(acc[i][j][2] + bb), (_Float16)(acc[i][j][3] + bb)};
        *(half4*)&vt[(size_t)vrow * L_SEQ + rbase] = h;
      }
    }
  }
}

// ---------------------------------------------------------------------------
// MFMA GEMM (NT) v2 (R7-verified): out-proj only.
// ---------------------------------------------------------------------------
template <int TM, int TN, int WR, int WC>
__global__ __launch_bounds__(256)
void gemm_mfma(const _Float16* __restrict__ A, const _Float16* __restrict__ B,
               const float* __restrict__ bias, float* __restrict__ C,
               int M, int N, int K) {
  constexpr int RT = TM / (16 * WR);
  constexpr int CT = TN / (16 * WC);
  constexpr int ACH = TM / 8;
  constexpr int NCH = (TM + TN) / 32;

  __shared__ _Float16 As[2][TM * 64];
  __shared__ _Float16 Bs[2][TN * 64];

  const int tid = threadIdx.x;
  const int wave = tid >> 6, lane = tid & 63;
  const int l15 = lane & 15, quad = lane >> 4;
  const int wr = wave / WC, wc = wave % WC;
  const int row0 = blockIdx.y * TM, col0 = blockIdx.x * TN;

  const int srow = lane >> 3;
  const int gc = (lane & 7) ^ srow;

  auto stage = [&](int buf, int k0) {
#pragma unroll
    for (int c = 0; c < NCH; ++c) {
      int chunk = wave * NCH + c;
      if (chunk < ACH) {
        int row = chunk * 8 + srow;
        gload16((const char*)(A + (size_t)(row0 + row) * K + k0) + gc * 16,
                (char*)&As[buf][0] + chunk * 1024);
      } else {
        int bch = chunk - ACH;
        int row = bch * 8 + srow;
        gload16((const char*)(B + (size_t)(col0 + row) * K + k0) + gc * 16,
                (char*)&Bs[buf][0] + bch * 1024);
      }
    }
  };

  floatx4 acc[RT][CT];
#pragma unroll
  for (int i = 0; i < RT; ++i)
#pragma unroll
    for (int j = 0; j < CT; ++j) acc[i][j] = (floatx4){0.f, 0.f, 0.f, 0.f};

  const int niter = K / 64;
  stage(0, 0);

  for (int it = 0; it < niter; ++it) {
    const int cur = it & 1;
    __syncthreads();
    if (it + 1 < niter) stage(cur ^ 1, (it + 1) * 64);

#pragma unroll
    for (int ks = 0; ks < 2; ++ks) {
      half8 af[RT], bf[CT];
#pragma unroll
      for (int t = 0; t < RT; ++t) {
        int r = wr * (16 * RT) + t * 16 + l15;
        af[t] = *(const half8*)&As[cur][r * 64 + (((ks * 4 + quad) ^ (r & 7)) * 8)];
      }
#pragma unroll
      for (int t = 0; t < CT; ++t) {
        int r = wc * (16 * CT) + t * 16 + l15;
        bf[t] = *(const half8*)&Bs[cur][r * 64 + (((ks * 4 + quad) ^ (r & 7)) * 8)];
      }
#pragma unroll
      for (int tr = 0; tr < RT; ++tr)
#pragma unroll
        for (int tc = 0; tc < CT; ++tc)
          acc[tr][tc] = __builtin_amdgcn_mfma_f32_16x16x32_f16(
              af[tr], bf[tc], acc[tr][tc], 0, 0, 0);
    }
  }

  const int crow = row0 + wr * (16 * RT);
  const int ccol = col0 + wc * (16 * CT);

#pragma unroll
  for (int tc = 0; tc < CT; ++tc) {
    int col = ccol + tc * 16 + l15;
    float bb = bias[col];
#pragma unroll
    for (int tr = 0; tr < RT; ++tr)
#pragma unroll
      for (int r = 0; r < 4; ++r)
        C[(size_t)(crow + tr * 16 + quad * 4 + r) * N + col] =
            acc[tr][tc][r] + bb;
  }
}

// ---------------------------------------------------------------------------
// MFMA flash attention v5 (proven 70us local optimum — rounds 1-5 all lost).
// Grid (H, L/128) = 256 blocks, 512 thr = 8 waves. Wave owns 16 q-rows.
// Bc=64 keys/iter, 32 iters, double-buffered K/V LDS, one barrier/iter,
// reg-prefetch of next tile + bias, S^T=K*Q^T trick, no-max softmax.
// ---------------------------------------------------------------------------
__global__ __launch_bounds__(512, 2)
void attn_mfma(const _Float16* __restrict__ qk, const _Float16* __restrict__ vt,
               const float* __restrict__ bias, _Float16* __restrict__ ctx) {
  const int h = blockIdx.x;
  const int q0 = blockIdx.y * 128;
  const int tid = threadIdx.x;
  const int wave = tid >> 6;
  const int lane = tid & 63;
  const int l15 = lane & 15;
  const int quad = lane >> 4;

  __shared__ _Float16 Ks[2][64][136];   // [buf][key][d]
  __shared__ _Float16 Vst[2][128][72];  // [buf][d][key]
  __shared__ _Float16 Ps[128][72];      // [q][key] (same-wave use only)

  // Q fragments (B-operand: B[k=quad*8+j][n=l15=q]):
  half8 qa[4];
  {
    const _Float16* qp = qk + (size_t)(q0 + wave * 16 + l15) * (2 * E_DIM) +
                         h * D_HEAD + quad * 8;
#pragma unroll
    for (int ks = 0; ks < 4; ++ks) qa[ks] = *(const half8*)(qp + ks * 32);
  }

  float l_i = 0.f;
  floatx4 o[8];
#pragma unroll
  for (int t = 0; t < 8; ++t) o[t] = (floatx4){0.f, 0.f, 0.f, 0.f};

  const float scale = 0.088388347648318447f;  // 1/sqrt(128)

  // staging (512 threads, 2 chunks each of K and V):
  half8 kreg[2], vreg[2];
  floatx4 bcur[4], bnxt[4];
#pragma unroll
  for (int c = 0; c < 2; ++c) {
    int m = c * 512 + tid;
    kreg[c] = *(const half8*)(qk + (size_t)(m >> 4) * (2 * E_DIM) + E_DIM +
                              h * D_HEAD + (m & 15) * 8);
    vreg[c] = *(const half8*)(vt + (size_t)(h * D_HEAD + (m >> 3)) * L_SEQ +
                              (m & 7) * 8);
  }
#pragma unroll
  for (int t = 0; t < 4; ++t)
    bcur[t] = *(const floatx4*)&bias[(size_t)(q0 + wave * 16 + l15) * L_SEQ +
                                    16 * t + quad * 4];
#pragma unroll
  for (int c = 0; c < 2; ++c) {
    int m = c * 512 + tid;
    *(half8*)&Ks[0][m >> 4][(m & 15) * 8] = kreg[c];
    *(half8*)&Vst[0][m >> 3][(m & 7) * 8] = vreg[c];
  }

#pragma unroll 2
  for (int it = 0; it < 32; ++it) {
    const int cur = it & 1, nxt = cur ^ 1;
    const int kt = it * 64;
    __syncthreads();  // buf[cur] writes visible; buf[nxt] readers (it-1) done

    if (it < 31) {
#pragma unroll
      for (int c = 0; c < 2; ++c) {
        int m = c * 512 + tid;
        kreg[c] = *(const half8*)(qk + (size_t)(kt + 64 + (m >> 4)) * (2 * E_DIM) +
                                  E_DIM + h * D_HEAD + (m & 15) * 8);
        vreg[c] = *(const half8*)(vt + (size_t)(h * D_HEAD + (m >> 3)) * L_SEQ +
                                  kt + 64 + (m & 7) * 8);
      }
#pragma unroll
      for (int t = 0; t < 4; ++t)
        bnxt[t] = *(const floatx4*)&bias[(size_t)(q0 + wave * 16 + l15) * L_SEQ +
                                         kt + 64 + 16 * t + quad * 4];
    }

    // ---- S^T = K Q^T : col=l15=q, row=quad*4+reg=key(within 16t) ----
    floatx4 st[4];
#pragma unroll
    for (int t = 0; t < 4; ++t) st[t] = (floatx4){0.f, 0.f, 0.f, 0.f};
#pragma unroll
    for (int ks = 0; ks < 4; ++ks)
#pragma unroll
      for (int t = 0; t < 4; ++t) {
        half8 kf = *(const half8*)&Ks[cur][16 * t + l15][ks * 32 + quad * 8];
        st[t] = __builtin_amdgcn_mfma_f32_16x16x32_f16(kf, qa[ks], st[t], 0, 0, 0);
      }

    // ---- softmax (no max subtraction) + P^T pack -> Ps[q][key] ----
    {
      float ls = 0.f;
      float ps[4][4];
#pragma unroll
      for (int t = 0; t < 4; ++t)
#pragma unroll
        for (int r = 0; r < 4; ++r) {
          float p = __expf(fmaf(st[t][r], scale, bcur[t][r]));
          ps[t][r] = p;
          ls += p;
        }
      ls += __shfl_xor(ls, 16);
      ls += __shfl_xor(ls, 32);
      l_i += ls;
#pragma unroll
      for (int t = 0; t < 4; ++t) {
        half4 hp = {(_Float16)ps[t][0], (_Float16)ps[t][1],
                    (_Float16)ps[t][2], (_Float16)ps[t][3]};
        *(half4*)&Ps[wave * 16 + l15][16 * t + quad * 4] = hp;
      }
    }

    // ---- O += P V (A=P own rows; B=V^T; same-wave, no barrier) ----
    half8 pa[2];
#pragma unroll
    for (int ks = 0; ks < 2; ++ks)
      pa[ks] = *(const half8*)&Ps[wave * 16 + l15][ks * 32 + quad * 8];
#pragma unroll
    for (int t = 0; t < 8; ++t)
#pragma unroll
      for (int ks = 0; ks < 2; ++ks) {
        half8 vf = *(const half8*)&Vst[cur][16 * t + l15][ks * 32 + quad * 8];
        o[t] = __builtin_amdgcn_mfma_f32_16x16x32_f16(pa[ks], vf, o[t], 0, 0, 0);
      }

    if (it < 31) {
#pragma unroll
      for (int c = 0; c < 2; ++c) {
        int m = c * 512 + tid;
        *(half8*)&Ks[nxt][m >> 4][(m & 15) * 8] = kreg[c];
        *(half8*)&Vst[nxt][m >> 3][(m & 7) * 8] = vreg[c];
      }
#pragma unroll
      for (int t = 0; t < 4; ++t) bcur[t] = bnxt[t];
    }
  }

  // ---- epilogue: ctx = O / l. l lives at lane l15=q; o rows are quad*4+r ----
  float inv[4];
#pragma unroll
  for (int r = 0; r < 4; ++r) inv[r] = 1.f / __shfl(l_i, quad * 4 + r);
#pragma unroll
  for (int t = 0; t < 8; ++t)
#pragma unroll
    for (int r = 0; r < 4; ++r) {
      int row = q0 + wave * 16 + quad * 4 + r;
      ctx[(size_t)row * E_DIM + h * D_HEAD + 16 * t + l15] =
          (_Float16)(o[t][r] * inv[r]);
    }
}

// ---------------------------------------------------------------------------
extern "C" void kernel_launch(void* const* d_in, const int* in_sizes, int n_in,
                              void* d_out, int out_size, void* d_ws, size_t ws_size,
                              hipStream_t stream) {
  const float* x          = (const float*)d_in[0];
  const float* bias_mat   = (const float*)d_in[1];
  const float* in_proj_w  = (const float*)d_in[2];
  const float* in_proj_b  = (const float*)d_in[3];
  const float* out_proj_w = (const float*)d_in[4];
  const float* out_proj_b = (const float*)d_in[5];
  float* out = (float*)d_out;

  _Float16* x16 = (_Float16*)d_ws;                         // L*E
  _Float16* w1  = x16 + (size_t)L_SEQ * E_DIM;             // 3E*E
  _Float16* w2  = w1 + (size_t)3 * E_DIM * E_DIM;          // E*E
  _Float16* qk  = w2 + (size_t)E_DIM * E_DIM;              // L*2E
  _Float16* vt  = qk + (size_t)L_SEQ * 2 * E_DIM;          // E*L
  _Float16* ctx = vt + (size_t)E_DIM * L_SEQ;              // L*E

  dim3 blk(256);
  const int nx = L_SEQ * E_DIM, nw1 = 3 * E_DIM * E_DIM, nw2 = E_DIM * E_DIM;

  cvt3_f32_f16<<<(nx + nw1 + nw2) / 2048, blk, 0, stream>>>(
      x, x16, nx, in_proj_w, w1, nw1, out_proj_w, w2, nw2);

  gemm_qkv<<<dim3(16, 16), dim3(512), 0, stream>>>(x16, w1, in_proj_b, qk, vt);

  attn_mfma<<<dim3(H_NUM, L_SEQ / 128), dim3(512), 0, stream>>>(qk, vt, bias_mat,
                                                                ctx);

  gemm_mfma<128, 64, 4, 1><<<dim3(E_DIM / 64, L_SEQ / 128), blk, 0, stream>>>(
      ctx, w2, out_proj_b, out, L_SEQ, E_DIM, E_DIM);
}